// Round 5
// baseline (1264.983 us; speedup 1.0000x reference)
//
#include <hip/hip_runtime.h>

// ---------------------------------------------------------------------------
// Qwen3Next GatedDeltaNet forward, MI355X/gfx950. v8:
//  - k_gemm_qkvz: register-pipelined 8-phase. Reads for phase p+1 issued in
//    phase p into double-buffered frag regs (afA/afB, bfA/bfB); compiler's
//    counted lgkmcnt lets next-phase LDS service hide under current MFMA.
//    ONE raw s_barrier per phase (was 2). vmcnt(2) at P3/P7 publishes the
//    next buffer before its reads are issued at P4/P8 (tail: vmcnt(0)).
//    Read schedule/phase: 4/8/0/12 x2. Stage schedule and swizzle = v7.
//  - XCD column map kept (FETCH 410->148 MB verified in v6).
// ---------------------------------------------------------------------------

typedef __attribute__((ext_vector_type(8))) __bf16 bf16x8;
typedef __attribute__((ext_vector_type(4))) float f32x4;
typedef __bf16 bf16_t;

#define MFMA_BF16(A, B, C) __builtin_amdgcn_mfma_f32_16x16x32_bf16((A), (B), (C), 0, 0, 0)

__device__ __forceinline__ void async16(const bf16_t* g, bf16_t* l) {
  __builtin_amdgcn_global_load_lds(
      (const __attribute__((address_space(1))) unsigned*)g,
      (__attribute__((address_space(3))) unsigned*)l, 16, 0, 0);
}

__device__ __forceinline__ bf16_t f2bf(float x) {
  unsigned u = __builtin_bit_cast(unsigned, x);
  unsigned r = u + 0x7fffu + ((u >> 16) & 1u);
  unsigned short s = (unsigned short)(r >> 16);
  return __builtin_bit_cast(bf16_t, s);
}
__device__ __forceinline__ float bf2f(bf16_t b) {
  unsigned short s = __builtin_bit_cast(unsigned short, b);
  unsigned u = ((unsigned)s) << 16;
  return __builtin_bit_cast(float, u);
}
__device__ __forceinline__ unsigned packhl(float x) {
  bf16_t h = f2bf(x);
  bf16_t l = f2bf(x - bf2f(h));
  return (((unsigned)__builtin_bit_cast(unsigned short, h)) << 16) |
         (unsigned)__builtin_bit_cast(unsigned short, l);
}
__device__ __forceinline__ float upk(unsigned u) {
  return __builtin_bit_cast(float, u & 0xffff0000u) +
         __builtin_bit_cast(float, u << 16);
}

struct FragPair { bf16x8 hi, lo; };

__device__ __forceinline__ void load8(float v[8], const float* p) {
  float4 a = *(const float4*)p;
  float4 b = *(const float4*)(p + 4);
  v[0] = a.x; v[1] = a.y; v[2] = a.z; v[3] = a.w;
  v[4] = b.x; v[5] = b.y; v[6] = b.z; v[7] = b.w;
}
__device__ __forceinline__ void load8u(unsigned v[8], const unsigned* p) {
  uint4 a = *(const uint4*)p;
  uint4 b = *(const uint4*)(p + 4);
  v[0] = a.x; v[1] = a.y; v[2] = a.z; v[3] = a.w;
  v[4] = b.x; v[5] = b.y; v[6] = b.z; v[7] = b.w;
}
__device__ __forceinline__ FragPair split8(const float v[8]) {
  FragPair f;
#pragma unroll
  for (int j = 0; j < 8; j++) {
    bf16_t h = f2bf(v[j]);
    f.hi[j] = h;
    f.lo[j] = f2bf(v[j] - bf2f(h));
  }
  return f;
}
__device__ __forceinline__ FragPair unpack8(const unsigned v[8]) {
  FragPair f;
#pragma unroll
  for (int j = 0; j < 8; j++) {
    f.hi[j] = __builtin_bit_cast(bf16_t, (unsigned short)(v[j] >> 16));
    f.lo[j] = __builtin_bit_cast(bf16_t, (unsigned short)(v[j] & 0xffffu));
  }
  return f;
}

// ---------------------------------------------------------------------------
// elementwise f32 -> bf16
__global__ void k_cvt(const float* __restrict__ in, bf16_t* __restrict__ out, int n) {
  int i = (blockIdx.x * 256 + threadIdx.x) * 4;
  if (i + 3 < n) {
    float4 v = *(const float4*)(in + i);
    out[i + 0] = f2bf(v.x); out[i + 1] = f2bf(v.y);
    out[i + 2] = f2bf(v.z); out[i + 3] = f2bf(v.w);
  }
}

// transpose [K][N] f32 -> [N][K] bf16
__global__ void k_transpose_cvt(const float* __restrict__ in, bf16_t* __restrict__ out,
                                int K, int N) {
  __shared__ bf16_t tile[64 * 65];
  int n0 = blockIdx.x * 64, k0 = blockIdx.y * 64;
  int c = threadIdx.x & 63, rg = threadIdx.x >> 6;
#pragma unroll
  for (int rr = 0; rr < 16; rr++) {
    int r = rr * 4 + rg;
    tile[c * 65 + r] = f2bf(in[(size_t)(k0 + r) * N + n0 + c]);
  }
  __syncthreads();
#pragma unroll
  for (int rr = 0; rr < 16; rr++) {
    int r = rr * 4 + rg;
    out[(size_t)(n0 + r) * K + k0 + c] = tile[r * 65 + c];
  }
}

// ---------------------------------------------------------------------------
// per-chunk k transpose: kb[s][2048] -> kbT[kh*64+ci][dk=128][s=64] bf16
__global__ void k_ktrans(const bf16_t* __restrict__ kb, bf16_t* __restrict__ kbT) {
  __shared__ __align__(16) bf16_t t[128][72];
  int kh = blockIdx.x >> 6, ci = blockIdx.x & 63, s0 = ci * 64;
  int s = threadIdx.x & 63, dg = threadIdx.x >> 6;
  const bf16_t* src = kb + (size_t)(s0 + s) * 2048 + kh * 128 + dg * 32;
#pragma unroll
  for (int j = 0; j < 4; j++) {
    bf16x8 v = *(const bf16x8*)(src + j * 8);
#pragma unroll
    for (int e = 0; e < 8; e++) t[dg * 32 + j * 8 + e][s] = v[e];
  }
  __syncthreads();
  int d = threadIdx.x >> 1, sh = (threadIdx.x & 1) * 32;
  bf16_t* dst = kbT + ((size_t)blockIdx.x * 128 + d) * 64 + sh;
#pragma unroll
  for (int j = 0; j < 4; j++)
    *(bf16x8*)(dst + j * 8) = *(const bf16x8*)(&t[d][sh + j * 8]);
}

// ---------------------------------------------------------------------------
// Old-structure swizzled GEMM (kept for t9: C[M,N]=A*BT^T fp32 out, 128^2 tile)
__global__ __launch_bounds__(256) void k_gemm(const bf16_t* __restrict__ A,
                                              const bf16_t* __restrict__ BT,
                                              float* __restrict__ C, int M, int N, int K) {
  __shared__ __align__(16) bf16_t sA[128 * 32];
  __shared__ __align__(16) bf16_t sB[128 * 32];
  const int tid = threadIdx.x;
  const int lane = tid & 63, w = tid >> 6;
  const int quad = lane >> 4, l15 = lane & 15;
  const int m0 = blockIdx.y * 128, n0 = blockIdx.x * 128;
  const int wm = (w >> 1) * 64, wn = (w & 1) * 64;
  f32x4 acc[4][4];
#pragma unroll
  for (int a = 0; a < 4; a++)
#pragma unroll
    for (int b = 0; b < 4; b++) { f32x4 z = {0.f, 0.f, 0.f, 0.f}; acc[a][b] = z; }
  const int sb = (lane & 7) ^ ((lane >> 3) & 7);
  const int srow = ((tid >> 3) << 1) + (sb >> 2);   // 0..63
  const int scol = (sb & 3) * 8;
  const bf16_t* gA = A + (size_t)(m0 + srow) * K + scol;
  const bf16_t* gB = BT + (size_t)(n0 + srow) * K + scol;
  bf16_t* lA = sA + w * 512;   // wave-uniform base; HW adds lane*16B
  bf16_t* lB = sB + w * 512;
  const int rh = l15 >> 1;
  const int bs = (((l15 & 1) << 2) + quad) ^ rh;
  const int foff = rh * 64 + bs * 8;
  for (int kt = 0; kt < K; kt += 32) {
    async16(gA + kt, lA);
    async16(gA + (size_t)64 * K + kt, lA + 2048);
    async16(gB + kt, lB);
    async16(gB + (size_t)64 * K + kt, lB + 2048);
    __syncthreads();
    bf16x8 af[4], bfv[4];
#pragma unroll
    for (int t = 0; t < 4; t++) {
      af[t]  = *(const bf16x8*)(sA + ((wm >> 1) + t * 8) * 64 + foff);
      bfv[t] = *(const bf16x8*)(sB + ((wn >> 1) + t * 8) * 64 + foff);
    }
#pragma unroll
    for (int mt = 0; mt < 4; mt++)
#pragma unroll
      for (int nt = 0; nt < 4; nt++)
        acc[mt][nt] = MFMA_BF16(af[mt], bfv[nt], acc[mt][nt]);
    __syncthreads();
  }
#pragma unroll
  for (int mt = 0; mt < 4; mt++)
#pragma unroll
    for (int nt = 0; nt < 4; nt++) {
      int row0 = m0 + wm + mt * 16 + quad * 4;
      int col = n0 + wn + nt * 16 + l15;
#pragma unroll
      for (int r = 0; r < 4; r++)
        C[(size_t)(row0 + r) * N + col] = acc[mt][nt][r];
    }
}

// ---------------------------------------------------------------------------
// GEMM1: register-pipelined 8-phase. 256x256 tile, BK=64, 512 thr / 8 waves
// (2Mx4N), per-wave 128x64. LDS: 2 buffers x {A0,A1,B0,B1} (16KB) = 128 KiB.
//
// Phase p: {s_barrier | issue ds_reads R(p+1) | issue 1 stg | [vmcnt@P3/P7]
//           | 16 MFMA on regs loaded at p-1 (compiler emits counted lgkm)}.
// Reads/phase: P1:4(bfB) P2:8(afB) P3:0 P4:12(afA+bfA,b1) P5:4 P6:8 P7:0
// P8:12(b0'). Stages: P1:b1A0 P2:b1A1 P3:b0B0' P4:b0B1' P5:b0A0' P6:b0A1'
// P7:b1B0' P8:b1B1'. vmcnt(2)@P3 retires thru P2 -> buf1 published for P4's
// reads; vmcnt(2)@P7 retires thru P6 -> buf0' published for P8's reads.
// WAR: stg target's last reader completed >=2 phases earlier (barrier chain).
// Reg WAR: afA written P4 (last use P2), afB P6 (P4), bfA P4 (P3), bfB P5 (P4).
__global__ __launch_bounds__(512, 2) void k_gemm_qkvz(const bf16_t* __restrict__ A,
                                                      const bf16_t* __restrict__ BT,
                                                      bf16_t* __restrict__ qkvb,
                                                      bf16_t* __restrict__ zb,
                                                      int M, int N, int K) {
  __shared__ __align__(16) bf16_t sL[2 * 4 * 8192];   // 128 KiB
  const int tid = threadIdx.x;
  const int lane = tid & 63, w = tid >> 6;
  const int quad = lane >> 4, l15 = lane & 15;

  // XCD column map (v6, verified): XCD x owns bx in [6x,6x+6), all by.
  int id = blockIdx.y * gridDim.x + blockIdx.x;
  const int xcd = id & 7, jj = id >> 3;
  const int bx = xcd * 6 + (jj % 6), by = jj / 6;
  const int m0 = by * 256, n0 = bx * 256;
  const int wm = (w >> 2) * 128, wn = (w & 3) * 64;
  const int hA = (w >> 2);             // 0/1: A half this wave reads
  const int hB = 2 + ((w & 3) >> 1);   // 2/3: B half this wave reads
  const int brow0 = wn & 64;           // row base within B half

  f32x4 acc[8][4];
#pragma unroll
  for (int m = 0; m < 8; m++)
#pragma unroll
    for (int n = 0; n < 4; n++) { f32x4 z = {0.f, 0.f, 0.f, 0.f}; acc[m][n] = z; }

  // staging source geometry (v7, verified): per lane row rbase(+64), phys
  // block lane&7 holding logical block (lane&7)^(row&7).
  const int rbase = w * 8 + (lane >> 3);
  const int sq = (lane & 7) ^ ((lane >> 3) & 7);
  const bf16_t* gb[4];
  gb[0] = A + (size_t)(m0 + rbase) * K + sq * 8;
  gb[1] = A + (size_t)(m0 + 128 + rbase) * K + sq * 8;
  gb[2] = BT + (size_t)(n0 + rbase) * K + sq * 8;
  gb[3] = BT + (size_t)(n0 + 128 + rbase) * K + sq * 8;
  const size_t j64 = (size_t)64 * K;

  // double-buffered fragment registers
  bf16x8 afA[4][2], afB[4][2], bfA[2][2], bfB[2][2];
  const int NI = K >> 7;   // iterations of 2 K-tiles (16 for K=2048)

  auto stg = [&](int cb, int h, int kt) {
    const bf16_t* s = gb[h] + (size_t)kt * 64;
    bf16_t* d = sL + (cb * 4 + h) * 8192 + w * 512;
    async16(s, d);
    async16(s + j64, d + 4096);
  };
  auto ldA = [&](int cb, int mg, bf16x8 (&dst)[4][2]) {
    const bf16_t* base = sL + (cb * 4 + hA) * 8192;
#pragma unroll
    for (int m = 0; m < 4; m++)
#pragma unroll
      for (int ks = 0; ks < 2; ks++)
        dst[m][ks] = *(const bf16x8*)(base + (mg * 64 + m * 16 + l15) * 64 +
                                      (((ks * 4 + quad) ^ (l15 & 7)) * 8));
  };
  auto ldB = [&](int cb, int ng, bf16x8 (&dst)[2][2]) {
    const bf16_t* base = sL + (cb * 4 + hB) * 8192;
#pragma unroll
    for (int n = 0; n < 2; n++)
#pragma unroll
      for (int ks = 0; ks < 2; ks++)
        dst[n][ks] = *(const bf16x8*)(base + (brow0 + ng * 32 + n * 16 + l15) * 64 +
                                      (((ks * 4 + quad) ^ (l15 & 7)) * 8));
  };
  auto mm = [&](int mg, int ng, bf16x8 (&A4)[4][2], bf16x8 (&B2)[2][2]) {
    __builtin_amdgcn_sched_barrier(0);   // pin MFMA below this phase's issues
    __builtin_amdgcn_s_setprio(1);
#pragma unroll
    for (int m = 0; m < 4; m++)
#pragma unroll
      for (int n = 0; n < 2; n++)
#pragma unroll
        for (int ks = 0; ks < 2; ks++)
          acc[mg * 4 + m][ng * 2 + n] =
              MFMA_BF16(A4[m][ks], B2[n][ks], acc[mg * 4 + m][ng * 2 + n]);
    __builtin_amdgcn_s_setprio(0);
    __builtin_amdgcn_sched_barrier(0);
  };

#define BARSB()                       \
  do {                                \
    __builtin_amdgcn_s_barrier();     \
    __builtin_amdgcn_sched_barrier(0);\
  } while (0)

  // prologue: buf0 all halves (kt0) + buf1 B halves (kt1); publish buf0;
  // issue R(P1) = afA+bfA from buf0.
  stg(0, 0, 0); stg(0, 1, 0); stg(0, 2, 0); stg(0, 3, 0);
  stg(1, 2, 1); stg(1, 3, 1);
  asm volatile("s_waitcnt vmcnt(4)" ::: "memory");   // buf0's 8 retired
  __builtin_amdgcn_s_barrier();
  ldA(0, 0, afA); ldB(0, 0, bfA);

  for (int i = 0; i < NI; ++i) {
    const int k2 = 2 * i;
    const bool more = (i + 1 < NI);
    // P1: MFMA Q1(b0) on afA,bfA; read bfB=bf23(b0); stage b1A0(kt+1)
    BARSB();
    ldB(0, 1, bfB);
    stg(1, 0, k2 + 1);
    mm(0, 0, afA, bfA);
    // P2: MFMA Q2(b0) on afA,bfB; read afB=afr1(b0); stage b1A1(kt+1)
    BARSB();
    ldA(0, 1, afB);
    stg(1, 1, k2 + 1);
    mm(0, 1, afA, bfB);
    // P3: MFMA Q3(b0) on afB,bfA; no reads; stage b0B0(kt+2); publish buf1
    BARSB();
    if (more) {
      stg(0, 2, k2 + 2);
      asm volatile("s_waitcnt vmcnt(2)" ::: "memory");  // thru P2: buf1 ready
    } else {
      asm volatile("s_waitcnt vmcnt(0)" ::: "memory");
    }
    mm(1, 0, afB, bfA);
    // P4: MFMA Q4(b0) on afB,bfB; read afA+bfA from buf1; stage b0B1(kt+2)
    BARSB();
    ldA(1, 0, afA); ldB(1, 0, bfA);
    if (more) stg(0, 3, k2 + 2);
    mm(1, 1, afB, bfB);
    // P5: MFMA Q1(b1) on afA,bfA; read bfB=bf23(b1); stage b0A0(kt+2)
    BARSB();
    ldB(1, 1, bfB);
    if (more) stg(0, 0, k2 + 2);
    mm(0, 0, afA, bfA);
    // P6: MFMA Q2(b1); read afB=afr1(b1); stage b0A1(kt+2)
    BARSB();
    ldA(1, 1, afB);
    if (more) stg(0, 1, k2 + 2);
    mm(0, 1, afA, bfB);
    // P7: MFMA Q3(b1); no reads; stage b1B0(kt+3); publish buf0'
    BARSB();
    if (more) {
      stg(1, 2, k2 + 3);
      asm volatile("s_waitcnt vmcnt(2)" ::: "memory");  // thru P6: buf0' ready
    } else {
      asm volatile("s_waitcnt vmcnt(0)" ::: "memory");
    }
    mm(1, 0, afB, bfA);
    // P8: MFMA Q4(b1); read afA+bfA from buf0' (next iter); stage b1B1(kt+3)
    BARSB();
    if (more) {
      ldA(0, 0, afA); ldB(0, 0, bfA);
      stg(1, 3, k2 + 3);
    }
    mm(1, 1, afB, bfB);
  }
#undef BARSB

  // epilogue: split columns into qkv (kh*512+rr) and z (kh*256+rr-512)
#pragma unroll
  for (int n = 0; n < 4; n++) {
    int c = n0 + wn + n * 16 + l15;        // 0..12287
    int kh = c / 768;
    int rr = c - kh * 768;
    bool isz = (rr >= 512);
    bf16_t* dst = isz ? zb : qkvb;
    size_t stride = isz ? 4096 : 8192;
    size_t coff = isz ? (size_t)(kh * 256 + (rr - 512)) : (size_t)(kh * 512 + rr);
#pragma unroll
    for (int m = 0; m < 8; m++) {
      int row0 = m0 + wm + m * 16 + quad * 4;
#pragma unroll
      for (int r = 0; r < 4; r++)
        dst[(size_t)(row0 + r) * stride + coff] = f2bf(acc[m][n][r]);
    }
  }
}

// ---------------------------------------------------------------------------
// ba = hs @ W_ba  ->  beta = sigmoid(b), g = -exp(A_log)*softplus(a+dt_bias)
__global__ __launch_bounds__(256) void k_ba(const float* __restrict__ hs,
                                            const float* __restrict__ Wba,
                                            const float* __restrict__ A_log,
                                            const float* __restrict__ dtb,
                                            float* __restrict__ g, float* __restrict__ beta) {
  __shared__ float sH[4][2048];
  int s0 = blockIdx.x * 32;
  int c = threadIdx.x & 63, sg = threadIdx.x >> 6;
  for (int rg = 0; rg < 8; rg++) {
    __syncthreads();
    for (int i = threadIdx.x; i < 2048; i += 256) {  // float4 units
      int r = i >> 9, kk = (i & 511) * 4;
      *(float4*)(&sH[r][kk]) = *(const float4*)(hs + (size_t)(s0 + rg * 4 + r) * 2048 + kk);
    }
    __syncthreads();
    float dot = 0.f;
    for (int kk = 0; kk < 2048; kk += 4) {
      float4 hv = *(const float4*)(&sH[sg][kk]);
      dot += hv.x * Wba[(kk + 0) * 64 + c] + hv.y * Wba[(kk + 1) * 64 + c] +
             hv.z * Wba[(kk + 2) * 64 + c] + hv.w * Wba[(kk + 3) * 64 + c];
    }
    int s = s0 + rg * 4 + sg;
    int hh = c >> 2, j = c & 3;
    if (j < 2) {
      int vh = hh * 2 + j;
      beta[s * 32 + vh] = 1.f / (1.f + __expf(-dot));
    } else {
      int vh = hh * 2 + (j - 2);
      float x = dot + dtb[vh];
      float sp = (x > 20.f) ? x : log1pf(__expf(x));
      g[s * 32 + vh] = -__expf(A_log[vh]) * sp;
    }
  }
}

// ---------------------------------------------------------------------------
// depthwise causal conv (KSZ=4) + silu; bf16 in (qkvb layout kh*512+r), bf16 out
__global__ void k_conv(const bf16_t* __restrict__ qkvb, const float* __restrict__ ck,
                       bf16_t* __restrict__ qb, bf16_t* __restrict__ kb,
                       bf16_t* __restrict__ vb) {
  int c = blockIdx.x * 256 + threadIdx.x;   // 0..8191 global conv channel
  int s0 = blockIdx.y * 128;
  int col, dstc, dstride;
  bf16_t* dst;
  float scale = 1.0f;
  if (c < 2048) {
    int hh = c >> 7, d = c & 127;
    col = hh * 512 + d; dst = qb; dstc = c; dstride = 2048;
    scale = 0.08838834764831845f;  // rsqrt(DK)
  } else if (c < 4096) {
    int cc = c - 2048, hh = cc >> 7, d = cc & 127;
    col = hh * 512 + 128 + d; dst = kb; dstc = cc; dstride = 2048;
  } else {
    int cc = c - 4096, vh = cc >> 7, d = cc & 127;
    col = (vh >> 1) * 512 + 256 + (vh & 1) * 128 + d; dst = vb; dstc = cc; dstride = 4096;
  }
  float w0 = ck[c], w1 = ck[8192 + c], w2 = ck[2 * 8192 + c], w3 = ck[3 * 8192 + c];
  float x0 = 0.f, x1 = 0.f, x2 = 0.f;
  if (s0 >= 3) {
    x0 = bf2f(qkvb[(size_t)(s0 - 3) * 8192 + col]);
    x1 = bf2f(qkvb[(size_t)(s0 - 2) * 8192 + col]);
    x2 = bf2f(qkvb[(size_t)(s0 - 1) * 8192 + col]);
  }
  for (int s = s0; s < s0 + 128; s++) {
    float x3 = bf2f(qkvb[(size_t)s * 8192 + col]);
    float y = w0 * x0 + w1 * x1 + w2 * x2 + w3 * x3;
    y = y / (1.f + __expf(-y));
    dst[(size_t)s * dstride + dstc] = f2bf(y * scale);
    x0 = x1; x1 = x2; x2 = x3;
  }
}

// ---------------------------------------------------------------------------
// phase A: per (head, chunk): L, attn=(I-L)^-1 via nilpotent squaring,
// vi = attn@(beta v) (f32), kcdn = -attn@(beta e^gc k) (bf16)
__global__ __launch_bounds__(256) void k_phaseA(const bf16_t* __restrict__ kb,
                                                const bf16_t* __restrict__ vb,
                                                const float* __restrict__ g,
                                                const float* __restrict__ beta,
                                                float* __restrict__ vi,
                                                bf16_t* __restrict__ kcdn) {
  __shared__ __align__(16) char smem[36608];
  float* sGc = (float*)smem;               // [64]
  float* sBt = (float*)(smem + 256);       // [64]
  float* sBE = (float*)(smem + 512);       // [64]
  float* sP  = (float*)(smem + 768);       // [64][68] f32 -> ends 18176
  bf16_t* sQ  = (bf16_t*)(smem + 18176);   // [64][72] -> ends 27392
  bf16_t* sQT = (bf16_t*)(smem + 27392);   // [64][72] -> ends 36608
  bf16_t* sVT = (bf16_t*)(smem + 18176);   // overlay (after squaring)
  bf16_t* sKT = (bf16_t*)(smem + 27392);   // overlay

  const int tid = threadIdx.x, lane = tid & 63, w = tid >> 6;
  const int quad = lane >> 4, l15 = lane & 15;
  const int h = blockIdx.x >> 6, ci = blockIdx.x & 63;
  const int kh = h >> 1, s0 = ci * 64;
  const int m = w * 16 + l15;

  if (tid < 64) {
    float gv = g[(size_t)(s0 + tid) * 32 + h];
    float bv = beta[(size_t)(s0 + tid) * 32 + h];
#pragma unroll
    for (int off = 1; off < 64; off <<= 1) {
      float t = __shfl_up(gv, off, 64);
      if (tid >= off) gv += t;
    }
    sGc[tid] = gv; sBt[tid] = bv; sBE[tid] = bv * __expf(gv);
  }
  __syncthreads();

  // ---- raw K@K^T (exact bf16 inputs) ----
  const bf16_t* krow = kb + (size_t)s0 * 2048 + kh * 128;
  bf16x8 ak[4];
#pragma unroll
  for (int ks = 0; ks < 4; ks++)
    ak[ks] = *(const bf16x8*)(krow + (size_t)m * 2048 + ks * 32 + quad * 8);
  f32x4 accL[4];
#pragma unroll
  for (int nt = 0; nt < 4; nt++) { f32x4 z = {0.f, 0.f, 0.f, 0.f}; accL[nt] = z; }
#pragma unroll
  for (int nt = 0; nt < 4; nt++)
#pragma unroll
    for (int ks = 0; ks < 4; ks++) {
      bf16x8 bk = *(const bf16x8*)(krow + (size_t)(nt * 16 + l15) * 2048 + ks * 32 + quad * 8);
      accL[nt] = MFMA_BF16(ak[ks], bk, accL[nt]);
    }
#pragma unroll
  for (int nt = 0; nt < 4; nt++) {
    int j = nt * 16 + l15;
#pragma unroll
    for (int r = 0; r < 4; r++) {
      int i = w * 16 + quad * 4 + r;
      float Lij = (i > j) ? (-accL[nt][r] * sBt[i] * __expf(sGc[i] - sGc[j])) : 0.f;
      sP[i * 68 + j] = ((i == j) ? 1.f : 0.f) + Lij;
      bf16_t q16 = f2bf(Lij);
      sQ[i * 72 + j] = q16;
      sQT[j * 72 + i] = q16;
    }
  }
  __syncthreads();

  // ---- attn = (I+L)(I+L^2)...(I+L^32); P holds running product ----
  for (int it = 0; it < 5; it++) {
    f32x4 accQ[4];
#pragma unroll
    for (int nt = 0; nt < 4; nt++) { f32x4 z = {0.f, 0.f, 0.f, 0.f}; accQ[nt] = z; }
    bf16x8 qa[2];
#pragma unroll
    for (int ks = 0; ks < 2; ks++)
      qa[ks] = *(const bf16x8*)(sQ + m * 72 + ks * 32 + quad * 8);
#pragma unroll
    for (int nt = 0; nt < 4; nt++)
#pragma unroll
      for (int ks = 0; ks < 2; ks++) {
        bf16x8 qv = *(const bf16x8*)(sQT + (nt * 16 + l15) * 72 + ks * 32 + quad * 8);
        accQ[nt] = MFMA_BF16(qa[ks], qv, accQ[nt]);
      }
    __syncthreads();
#pragma unroll
    for (int nt = 0; nt < 4; nt++) {
      int j = nt * 16 + l15;
#pragma unroll
      for (int r = 0; r < 4; r++) {
        int i = w * 16 + quad * 4 + r;
        bf16_t q16 = f2bf(accQ[nt][r]);
        sQ[i * 72 + j] = q16;
        sQT[j * 72 + i] = q16;
      }
    }
    __syncthreads();
    // P += P @ Q (wave owns its 16 rows -> in-place safe)
    f32x4 accP[4];
#pragma unroll
    for (int nt = 0; nt < 4; nt++) { f32x4 z = {0.f, 0.f, 0.f, 0.f}; accP[nt] = z; }
    FragPair pa[2];
#pragma unroll
    for (int ks = 0; ks < 2; ks++) {
      float v[8];
      load8(v, sP + m * 68 + ks * 32 + quad * 8);
      pa[ks] = split8(v);
    }
#pragma unroll
    for (int nt = 0; nt < 4; nt++)
#pragma unroll
      for (int ks = 0; ks < 2; ks++) {
        bf16x8 qv = *(const bf16x8*)(sQT + (nt * 16 + l15) * 72 + ks * 32 + quad * 8);
        accP[nt] = MFMA_BF16(pa[ks].hi, qv, accP[nt]);
        accP[nt] = MFMA_BF16(pa[ks].lo, qv, accP[nt]);
      }
#pragma unroll
    for (int nt = 0; nt < 4; nt++) {
      int j = nt * 16 + l15;
#pragma unroll
      for (int r = 0; r < 4; r++) {
        int i = w * 16 + quad * 4 + r;
        sP[i * 68 + j] += accP[nt][r];
      }
    }
  }

  // ---- A-operand splits: attn*beta (for vi) and attn*beta*e^gc (for kcd) ----
  FragPair paV[2], paK[2];
#pragma unroll
  for (int ks = 0; ks < 2; ks++) {
    float v[8];
    load8(v, sP + m * 68 + ks * 32 + quad * 8);
    float vv[8], vk[8];
#pragma unroll
    for (int jj = 0; jj < 8; jj++) {
      int i = ks * 32 + quad * 8 + jj;
      vv[jj] = v[jj] * sBt[i];
      vk[jj] = v[jj] * sBE[i];
    }
    paV[ks] = split8(vv);
    paK[ks] = split8(vk);
  }

  // ---- vi / kcdn in two dv halves (sVT/sKT overlay sQ/sQT) ----
  for (int hf = 0; hf < 2; hf++) {
    __syncthreads();  // prior sQT/sVT/sKT readers done before overwrite
    {
      int sidx = tid & 63, dg = tid >> 6;
      const bf16_t* vsrc = vb + (size_t)(s0 + sidx) * 4096 + h * 128 + hf * 64 + dg * 16;
      const bf16_t* ksrc = kb + (size_t)(s0 + sidx) * 2048 + kh * 128 + hf * 64 + dg * 16;
      bf16x8 v0 = *(const bf16x8*)vsrc;
      bf16x8 v1 = *(const bf16x8*)(vsrc + 8);
      bf16x8 k0 = *(const bf16x8*)ksrc;
      bf16x8 k1 = *(const bf16x8*)(ksrc + 8);
#pragma unroll
      for (int e = 0; e < 8; e++) {
        sVT[(dg * 16 + e) * 72 + sidx] = v0[e];
        sVT[(dg * 16 + 8 + e) * 72 + sidx] = v1[e];
        sKT[(dg * 16 + e) * 72 + sidx] = k0[e];
        sKT[(dg * 16 + 8 + e) * 72 + sidx] = k1[e];
      }
    }
    __syncthreads();
    f32x4 accV[4], accK[4];
#pragma unroll
    for (int nt = 0; nt < 4; nt++) {
      f32x4 z = {0.f, 0.f, 0.f, 0.f};
      accV[nt] = z; accK[nt] = z;
    }
#pragma unroll
    for (int nt = 0; nt < 4; nt++)
#pragma unroll
      for (int ks = 0; ks < 2; ks++) {
        bf16x8 bv = *(const bf16x8*)(sVT + (nt * 16 + l15) * 72 + ks * 32 + quad * 8);
        accV[nt] = MFMA_BF16(paV[ks].hi, bv, accV[nt]);
        accV[nt] = MFMA_BF16(paV[ks].lo, bv, accV[nt]);
        bf16x8 bk = *(const bf16x8*)(sKT + (nt * 16 + l15) * 72 + ks * 32 + quad * 8);
        accK[nt] = MFMA_BF16(paK[ks].hi, bk, accK[nt]);
        accK[nt] = MFMA_BF16(paK[ks].lo, bk, accK[nt]);
      }
#pragma unroll
    for (int nt = 0; nt < 4; nt++) {
      int col = hf * 64 + nt * 16 + l15;
#pragma unroll
      for (int r = 0; r < 4; r++) {
        int row = w * 16 + quad * 4 + r;
        size_t o = ((size_t)h * 4096 + s0 + row) * 128 + col;
        vi[o] = accV[nt][r];
        kcdn[o] = f2bf(-accK[nt][r]);
      }
    }
  }
}

// ---------------------------------------------------------------------------
// phase B: sequential 64-chunk scan. grid = 32 heads x 8 col-groups (16 dv).
__global__ __launch_bounds__(256) void k_phaseB(const bf16_t* __restrict__ qb,
                                                const bf16_t* __restrict__ kbT,
                                                const float* __restrict__ g,
                                                const float* __restrict__ vi,
                                                const bf16_t* __restrict__ kcdn,
                                                bf16_t* __restrict__ vnT,
                                                bf16_t* __restrict__ outp) {
  __shared__ __align__(16) char smem[13312];
  float* sGc2 = (float*)smem;                 // [2][64] -> 512
  unsigned* sSTp = (unsigned*)(smem + 512);   // [16][132] -> ends 8960
  unsigned* sVTp = (unsigned*)(smem + 8960);  // [16][68] -> ends 13312
  const int tid = threadIdx.x, lane = tid & 63, w = tid >> 6;
  const int quad = lane >> 4, l15 = lane & 15;
  const int h = blockIdx.x >> 3, cg = blockIdx.x & 7;
  const int kh = h >> 1, col0 = cg * 16;
  const int m = w * 16 + l15;

  for (int i = tid; i < 16 * 132; i += 256) sSTp[i] = 0u;
  if (tid < 64) {
    float gv = g[(size_t)tid * 32 + h];
#pragma unroll
    for (int off = 1; off < 64; off <<= 1) {
      float t = __shfl_up(gv, off, 64);
      if (tid >= off) gv += t;
    }
    sGc2[tid] = gv;
  }
  __syncthreads();

  for (int ci = 0; ci < 64; ci++) {
    const int s0 = ci * 64;
    const float* sGc = sGc2 + (ci & 1) * 64;

    // per-chunk global fragments (state-independent; overlap with ds_reads)
    const bf16_t* kcrow = kcdn + ((size_t)h * 4096 + s0 + m) * 128;
    const bf16_t* qrow = qb + (size_t)(s0 + m) * 2048 + kh * 128;
    bf16x8 a1[4], a2[4], kT[2][2];
#pragma unroll
    for (int d = 0; d < 4; d++) {
      a1[d] = *(const bf16x8*)(kcrow + d * 32 + quad * 8);
      a2[d] = *(const bf16x8*)(qrow + d * 32 + quad * 8);
    }
#pragma unroll
    for (int mi = 0; mi < 2; mi++)
#pragma unroll
      for (int ks = 0; ks < 2; ks++)
        kT[mi][ks] = *(const bf16x8*)(kbT + ((size_t)(kh * 64 + ci) * 128 +
                                             w * 32 + mi * 16 + l15) * 64 + ks * 32 + quad * 8);
    const int colg = col0 + l15;
    size_t vbase = ((size_t)h * 4096 + s0 + w * 16 + quad * 4) * 128 + colg;
    f32x4 accV = {vi[vbase], vi[vbase + 128], vi[vbase + 256], vi[vbase + 384]};
    f32x4 accO = {0.f, 0.f, 0.f, 0.f};
#pragma unroll
    for (int d = 0; d < 4; d++) {
      unsigned u[8];
      load8u(u, sSTp + l15 * 132 + d * 32 + quad * 8);
      FragPair B = unpack8(u);
      accV = MFMA_BF16(a1[d], B.hi, accV);
      accV = MFMA_BF16(a1[d], B.lo, accV);
      accO = MFMA_BF16(a2[d], B.hi, accO);
      accO = MFMA_BF16(a2[d], B.lo, accO);
    }
    const float gl = sGc[63];
    {
      bf16_t* vout = vnT + ((size_t)(h * 64 + ci) * 128 + colg) * 64 + w * 16 + quad * 4;
      bf16_t* oout = outp + vbase;
      ushort4 vv;
      unsigned pk[4];
      unsigned short vb_[4];
#pragma unroll
      for (int r = 0; r < 4; r++) {
        float gr = sGc[w * 16 + quad * 4 + r];
        oout[(size_t)r * 128] = f2bf(accO[r] * __expf(gr));
        vb_[r] = __builtin_bit_cast(unsigned short, f2bf(accV[r]));
        pk[r] = packhl(accV[r] * __expf(gl - gr));  // fold decay into v_new
      }
      vv.x = vb_[0]; vv.y = vb_[1]; vv.z = vb_[2]; vv.w = vb_[3];
      *(ushort4*)vout = vv;
      uint4 pv; pv.x = pk[0]; pv.y = pk[1]; pv.z = pk[2]; pv.w = pk[3];
      *(uint4*)(sVTp + l15 * 68 + w * 16 + quad * 4) = pv;
    }
    __syncthreads();  // state reads done + sVTp visible

    // state = state*e^gl + kT @ (decayed v_new)
    f32x4 accD[2];
#pragma unroll
    for (int mi = 0; mi < 2; mi++) { f32x4 z = {0.f, 0.f, 0.f, 0.f}; accD[mi] = z; }
#pragma unroll
    for (int ks = 0; ks < 2; ks++) {
      unsigned u[8];
      load8u(u, sVTp + l15 * 68 + ks * 32 + quad * 8);
      FragPair Bv = unpack8(u);
#pragma unroll
      for (int mi = 0; mi < 2; mi++) {
        accD[mi] = MFMA_BF16(kT[mi][ks], Bv.hi, accD[mi]);
        accD[mi] = MFMA_BF16(kT[mi][ks], Bv.lo, accD[mi]);
      }
    }
    float egl = __expf(gl);
#pragma unroll
    for (int mi = 0; mi < 2; mi++) {
      int row0 = w * 32 + mi * 16 + quad * 4;
      unsigned* ps = sSTp + l15 * 132 + row0;
      uint4 old4 = *(uint4*)ps;
      uint4 nu;
      nu.x = packhl(upk(old4.x) * egl + accD[mi][0]);
      nu.y = packhl(upk(old4.y) * egl + accD[mi][1]);
      nu.z = packhl(upk(old4.z) * egl + accD[mi][2]);
      nu.w = packhl(upk(old4.w) * egl + accD[mi][3]);
      *(uint4*)ps = nu;
    }
    // next chunk's gcum into the other sGc buffer (race-free: other half)
    if (ci + 1 < 64 && tid < 64) {
      float gv = g[(size_t)((ci + 1) * 64 + tid) * 32 + h];
#pragma unroll
      for (int off = 1; off < 64; off <<= 1) {
        float t = __shfl_up(gv, off, 64);
        if (tid >= off) gv += t;
      }
      sGc2[((ci + 1) & 1) * 64 + tid] = gv;
    }
    __syncthreads();
  }
}

// ---------------------------------------------------------------------------
// phase C: a = tril(q@k^T * decay); out = outp + a @ v_new; gated RMSNorm -> xf bf16
__global__ __launch_bounds__(256) void k_phaseC(const bf16_t* __restrict__ qb,
                                                const bf16_t* __restrict__ kb,
                                                const float* __restrict__ g,
                                                const bf16_t* __restrict__ vnT,
                                                const bf16_t* __restrict__ outp,
                                                const bf16_t* __restrict__ zb,
                                                const float* __restrict__ nw,
                                                bf16_t* __restrict__ xf) {
  __shared__ __align__(16) char smem[17664];
  float* sGc = (float*)smem;                 // [64]
  unsigned* sAp = (unsigned*)(smem + 256);   // [64][68] hi/lo packed
  const int tid = threadIdx.x, lane = tid & 63, w = tid >> 6;
  const int quad = lane >> 4, l15 = lane & 15;
  const int h = blockIdx.x >> 6, ci = blockIdx.x & 63;
  const int kh = h >> 1, s0 = ci * 64;
  const int m = w * 16 + l15;

  if (tid < 64) {
    float gv = g[(size_t)(s0 + tid) * 32 + h];
#pragma unroll
    for (int off = 1; off < 64; off <<= 1) {
      float t = __shfl_up(gv, off, 64);
      if (tid >= off) gv += t;
    }
    sGc[tid] = gv;
  }
  __syncthreads();

  const bf16_t* qrow = qb + (size_t)s0 * 2048 + kh * 128;
  const bf16_t* krow = kb + (size_t)s0 * 2048 + kh * 128;
  bf16x8 aq[4];
#pragma unroll
  for (int ks = 0; ks < 4; ks++)
    aq[ks] = *(const bf16x8*)(qrow + (size_t)m * 2048 + ks * 32 + quad * 8);
  f32x4 accA[4];
#pragma unroll
  for (int nt = 0; nt < 4; nt++) { f32x4 z = {0.f, 0.f, 0.f, 0.f}; accA[nt] = z; }
#pragma unroll
  for (int nt = 0; nt < 4; nt++)
#pragma unroll
    for (int ks = 0; ks < 4; ks++) {
      bf16x8 bk = *(const bf16x8*)(krow + (size_t)(nt * 16 + l15) * 2048 + ks * 32 + quad * 8);
      accA[nt] = MFMA_BF16(aq[ks], bk, accA[nt]);
    }
#pragma unroll
  for (int nt = 0; nt < 4; nt++) {
    int j = nt * 16 + l15;
#pragma unroll
    for (int r = 0; r < 4; r++) {
      int i = w * 16 + quad * 4 + r;
      float a = (i >= j) ? accA[nt][r] * __expf(sGc[i] - sGc[j]) : 0.f;
      sAp[i * 68 + j] = packhl(a);
    }
  }
  __syncthreads();

  FragPair Aa[2];
#pragma unroll
  for (int ks = 0; ks < 2; ks++) {
    unsigned u[8];
    load8u(u, sAp + m * 68 + ks * 32 + quad * 8);
    Aa[ks] = unpack8(u);
  }
  f32x4 accO[8];
#pragma unroll
  for (int nt = 0; nt < 8; nt++) {
    size_t base = ((size_t)h * 4096 + s0 + w * 16 + quad * 4) * 128 + nt * 16 + l15;
    f32x4 z;
    z[0] = bf2f(outp[base]); z[1] = bf2f(outp[base + 128]);
    z[2] = bf2f(outp[base + 256]); z[3] = bf2f(outp[base + 384]);
    accO[nt] = z;
  }
#pragma unroll
  for (int nt = 0; nt < 8; nt++)
#pragma unroll
    for (int ks = 0; ks < 2; ks++) {
      bf16x8 bv = *(const bf16x8*)(vnT + ((size_t)(h * 64 + ci) * 128 + nt * 16 + l15) * 64 +
                                   ks * 32 + quad * 8);
      accO[nt] = MFMA_BF16(Aa[ks].hi, bv, accO[nt]);
      accO[nt] = MFMA_BF16(Aa[ks].lo, bv, accO[nt]);
    }

  // gated RMSNorm: xf = core*silu(z); xf *= rsqrt(mean(xf^2)+eps)*norm_w
  float xv[8][4];
  float ss[4] = {0.f, 0.f, 0.f, 0.f};
#pragma unroll
  for (int nt = 0; nt < 8; nt++) {
    int dv = nt * 16 + l15;
#pragma unroll
    for (int r = 0; r < 4; r++) {
      int s = s0 + w * 16 + quad * 4 + r;
      float z = bf2f(zb[(size_t)s * 4096 + h * 128 + dv]);
      float gate = z / (1.f + __expf(-z));
      float val = accO[nt][r] * gate;
      xv[nt][r] = val;
      ss[r] += val * val;
    }
  }
#pragma unroll
  for (int off = 1; off < 16; off <<= 1) {
#pragma unroll
    for (int r = 0; r < 4; r++) ss[r] += __shfl_xor(ss[r], off, 64);
  }
  float rs[4];
#pragma unroll
  for (int r = 0; r < 4; r++) rs[r] = rsqrtf(ss[r] * (1.f / 128.f) + 1e-6f);
#pragma unroll
  for (int nt = 0; nt < 8; nt++) {
    int dv = nt * 16 + l15;
    float nwv = nw[dv];
#pragma unroll
    for (int r = 0; r < 4; r++) {
      int s = s0 + w * 16 + quad * 4 + r;
      xf[(size_t)s * 4096 + h * 128 + dv] = f2bf(xv[nt][r] * rs[r] * nwv);
    }
  }
}

// ---------------------------------------------------------------------------
extern "C" void kernel_launch(void* const* d_in, const int* in_sizes, int n_in,
                              void* d_out, int out_size, void* d_ws, size_t ws_size,
                              hipStream_t stream) {
  const float* hs = (const float*)d_in[0];
  const float* Wqkvz = (const float*)d_in[1];
  const float* Wba = (const float*)d_in[2];
  const float* convk = (const float*)d_in[3];
  const float* A_log = (const float*)d_in[4];
  const float* dtb = (const float*)d_in[5];
  const float* nw = (const float*)d_in[6];
  const float* Wout = (const float*)d_in[7];
  float* out = (float*)d_out;
  char* ws = (char*)d_ws;

  // Arena: 252,706,816 B with static aliasing.
  const size_t NEED = 252706816u;
  if (ws_size < NEED) return;  // diagnostic: absmax==max|ref| => ws too small

  bf16_t* hsbf = (bf16_t*)(ws + 0);              // 16.78 MB [t1-t2]
  bf16_t* wqkT = (bf16_t*)(ws + 16777216);       // 50.33 MB [t1-t2]
  bf16_t* qb   = (bf16_t*)(ws + 0);              // 16.78 MB [t4-t7] (over hsbf)
  bf16_t* kb   = (bf16_t*)(ws + 16777216);       // 16.78 MB [t4-t7] (over wqkT)
  bf16_t* vb   = (bf16_t*)(ws + 33554432);       // 33.55 MB [t4-t5] (over wqkT)
  bf16_t* vnT  = (bf16_t*)(ws + 33554432);       // 33.55 MB [t6-t7] (over vb)
  bf16_t* qkvb = (bf16_t*)(ws + 67108864);       // 67.11 MB [t2-t4]
  float*  vi   = (float*)(ws + 67108864);        // 67.11 MB [t5-t6] (over qkvb)
  bf16_t* xf   = (bf16_t*)(ws + 67108864);       // 33.55 MB [t7-t9] (over vi)
  bf16_t* zb   = (bf16_t*)(ws + 134217728);      // 33.55 MB [t2-t7]
  float*  gbuf = (float*)(ws + 167772160);       // 0.52 MB
  float*  bbuf = (float*)(ws + 168296448);       // 0.52 MB
  bf16_t* kcdn = (bf16_t*)(ws + 168820736);      // 33.55 MB [t5-t6]
  bf16_t* woutT= (bf16_t*)(ws + 168820736);      // 16.78 MB [t8-t9] (over kcdn)
  bf16_t* outp = (bf16_t*)(ws + 202375168);      // 33.55 MB [t6-t7]
  bf16_t* kbT  = (bf16_t*)(ws + 235929600);      // 16.78 MB [t4.5-t6] -> ends 252,706,816

  k_cvt<<<8192, 256, 0, stream>>>(hs, hsbf, 4096 * 2048);                      // t1
  k_transpose_cvt<<<dim3(192, 32), 256, 0, stream>>>(Wqkvz, wqkT, 2048, 12288);
  k_gemm_qkvz<<<dim3(48, 16), 512, 0, stream>>>(hsbf, wqkT, qkvb, zb,          // t2
                                                4096, 12288, 2048);
  k_ba<<<128, 256, 0, stream>>>(hs, Wba, A_log, dtb, gbuf, bbuf);              // t3
  k_conv<<<dim3(32, 32), 256, 0, stream>>>(qkvb, convk, qb, kb, vb);           // t4
  k_ktrans<<<1024, 256, 0, stream>>>(kb, kbT);                                 // t4.5
  k_phaseA<<<2048, 256, 0, stream>>>(kb, vb, gbuf, bbuf, vi, kcdn);            // t5
  k_phaseB<<<256, 256, 0, stream>>>(qb, kbT, gbuf, vi, kcdn, vnT, outp);       // t6
  k_phaseC<<<2048, 256, 0, stream>>>(qb, kb, gbuf, vnT, outp, zb, nw, xf);     // t7
  k_transpose_cvt<<<dim3(32, 64), 256, 0, stream>>>(Wout, woutT, 4096, 2048);  // t8
  k_gemm<<<dim3(16, 32), 256, 0, stream>>>(xf, woutT, out, 4096, 2048, 4096);  // t9
}

// Round 6
// 1030.676 us; speedup vs baseline: 1.2273x; 1.2273x over previous
//
#include <hip/hip_runtime.h>

// ---------------------------------------------------------------------------
// Qwen3Next GatedDeltaNet forward, MI355X/gfx950. v9:
//  - k_gemm_qkvz = v7's 8-phase schedule with ALL sched_barrier(0) pins
//    REMOVED (m141: order-pinning defeats hipcc's own counted-lgkm
//    scheduling, 1.7x). Template-faithful phase body: {ds_read subtile |
//    stage 1 half-tile | [lgkm8] | s_barrier | lgkm0 | setprio+16 MFMA |
//    s_barrier}; counted vmcnt(4) at Ph4/Ph8 (2 half-tiles in flight),
//    drain 0 only at tail. v8's register pipelining reverted (spill:
//    WRITE_SIZE 216->588 MB, dur 235->470 us).
//  - XCD column map kept (FETCH 410->148 MB verified in v6).
// ---------------------------------------------------------------------------

typedef __attribute__((ext_vector_type(8))) __bf16 bf16x8;
typedef __attribute__((ext_vector_type(4))) float f32x4;
typedef __bf16 bf16_t;

#define MFMA_BF16(A, B, C) __builtin_amdgcn_mfma_f32_16x16x32_bf16((A), (B), (C), 0, 0, 0)

__device__ __forceinline__ void async16(const bf16_t* g, bf16_t* l) {
  __builtin_amdgcn_global_load_lds(
      (const __attribute__((address_space(1))) unsigned*)g,
      (__attribute__((address_space(3))) unsigned*)l, 16, 0, 0);
}

__device__ __forceinline__ bf16_t f2bf(float x) {
  unsigned u = __builtin_bit_cast(unsigned, x);
  unsigned r = u + 0x7fffu + ((u >> 16) & 1u);
  unsigned short s = (unsigned short)(r >> 16);
  return __builtin_bit_cast(bf16_t, s);
}
__device__ __forceinline__ float bf2f(bf16_t b) {
  unsigned short s = __builtin_bit_cast(unsigned short, b);
  unsigned u = ((unsigned)s) << 16;
  return __builtin_bit_cast(float, u);
}
__device__ __forceinline__ unsigned packhl(float x) {
  bf16_t h = f2bf(x);
  bf16_t l = f2bf(x - bf2f(h));
  return (((unsigned)__builtin_bit_cast(unsigned short, h)) << 16) |
         (unsigned)__builtin_bit_cast(unsigned short, l);
}
__device__ __forceinline__ float upk(unsigned u) {
  return __builtin_bit_cast(float, u & 0xffff0000u) +
         __builtin_bit_cast(float, u << 16);
}

struct FragPair { bf16x8 hi, lo; };

__device__ __forceinline__ void load8(float v[8], const float* p) {
  float4 a = *(const float4*)p;
  float4 b = *(const float4*)(p + 4);
  v[0] = a.x; v[1] = a.y; v[2] = a.z; v[3] = a.w;
  v[4] = b.x; v[5] = b.y; v[6] = b.z; v[7] = b.w;
}
__device__ __forceinline__ void load8u(unsigned v[8], const unsigned* p) {
  uint4 a = *(const uint4*)p;
  uint4 b = *(const uint4*)(p + 4);
  v[0] = a.x; v[1] = a.y; v[2] = a.z; v[3] = a.w;
  v[4] = b.x; v[5] = b.y; v[6] = b.z; v[7] = b.w;
}
__device__ __forceinline__ FragPair split8(const float v[8]) {
  FragPair f;
#pragma unroll
  for (int j = 0; j < 8; j++) {
    bf16_t h = f2bf(v[j]);
    f.hi[j] = h;
    f.lo[j] = f2bf(v[j] - bf2f(h));
  }
  return f;
}
__device__ __forceinline__ FragPair unpack8(const unsigned v[8]) {
  FragPair f;
#pragma unroll
  for (int j = 0; j < 8; j++) {
    f.hi[j] = __builtin_bit_cast(bf16_t, (unsigned short)(v[j] >> 16));
    f.lo[j] = __builtin_bit_cast(bf16_t, (unsigned short)(v[j] & 0xffffu));
  }
  return f;
}

// ---------------------------------------------------------------------------
// elementwise f32 -> bf16
__global__ void k_cvt(const float* __restrict__ in, bf16_t* __restrict__ out, int n) {
  int i = (blockIdx.x * 256 + threadIdx.x) * 4;
  if (i + 3 < n) {
    float4 v = *(const float4*)(in + i);
    out[i + 0] = f2bf(v.x); out[i + 1] = f2bf(v.y);
    out[i + 2] = f2bf(v.z); out[i + 3] = f2bf(v.w);
  }
}

// transpose [K][N] f32 -> [N][K] bf16
__global__ void k_transpose_cvt(const float* __restrict__ in, bf16_t* __restrict__ out,
                                int K, int N) {
  __shared__ bf16_t tile[64 * 65];
  int n0 = blockIdx.x * 64, k0 = blockIdx.y * 64;
  int c = threadIdx.x & 63, rg = threadIdx.x >> 6;
#pragma unroll
  for (int rr = 0; rr < 16; rr++) {
    int r = rr * 4 + rg;
    tile[c * 65 + r] = f2bf(in[(size_t)(k0 + r) * N + n0 + c]);
  }
  __syncthreads();
#pragma unroll
  for (int rr = 0; rr < 16; rr++) {
    int r = rr * 4 + rg;
    out[(size_t)(n0 + r) * K + k0 + c] = tile[r * 65 + c];
  }
}

// ---------------------------------------------------------------------------
// per-chunk k transpose: kb[s][2048] -> kbT[kh*64+ci][dk=128][s=64] bf16
__global__ void k_ktrans(const bf16_t* __restrict__ kb, bf16_t* __restrict__ kbT) {
  __shared__ __align__(16) bf16_t t[128][72];
  int kh = blockIdx.x >> 6, ci = blockIdx.x & 63, s0 = ci * 64;
  int s = threadIdx.x & 63, dg = threadIdx.x >> 6;
  const bf16_t* src = kb + (size_t)(s0 + s) * 2048 + kh * 128 + dg * 32;
#pragma unroll
  for (int j = 0; j < 4; j++) {
    bf16x8 v = *(const bf16x8*)(src + j * 8);
#pragma unroll
    for (int e = 0; e < 8; e++) t[dg * 32 + j * 8 + e][s] = v[e];
  }
  __syncthreads();
  int d = threadIdx.x >> 1, sh = (threadIdx.x & 1) * 32;
  bf16_t* dst = kbT + ((size_t)blockIdx.x * 128 + d) * 64 + sh;
#pragma unroll
  for (int j = 0; j < 4; j++)
    *(bf16x8*)(dst + j * 8) = *(const bf16x8*)(&t[d][sh + j * 8]);
}

// ---------------------------------------------------------------------------
// Old-structure swizzled GEMM (kept for t9: C[M,N]=A*BT^T fp32 out, 128^2 tile)
__global__ __launch_bounds__(256) void k_gemm(const bf16_t* __restrict__ A,
                                              const bf16_t* __restrict__ BT,
                                              float* __restrict__ C, int M, int N, int K) {
  __shared__ __align__(16) bf16_t sA[128 * 32];
  __shared__ __align__(16) bf16_t sB[128 * 32];
  const int tid = threadIdx.x;
  const int lane = tid & 63, w = tid >> 6;
  const int quad = lane >> 4, l15 = lane & 15;
  const int m0 = blockIdx.y * 128, n0 = blockIdx.x * 128;
  const int wm = (w >> 1) * 64, wn = (w & 1) * 64;
  f32x4 acc[4][4];
#pragma unroll
  for (int a = 0; a < 4; a++)
#pragma unroll
    for (int b = 0; b < 4; b++) { f32x4 z = {0.f, 0.f, 0.f, 0.f}; acc[a][b] = z; }
  const int sb = (lane & 7) ^ ((lane >> 3) & 7);
  const int srow = ((tid >> 3) << 1) + (sb >> 2);   // 0..63
  const int scol = (sb & 3) * 8;
  const bf16_t* gA = A + (size_t)(m0 + srow) * K + scol;
  const bf16_t* gB = BT + (size_t)(n0 + srow) * K + scol;
  bf16_t* lA = sA + w * 512;   // wave-uniform base; HW adds lane*16B
  bf16_t* lB = sB + w * 512;
  const int rh = l15 >> 1;
  const int bs = (((l15 & 1) << 2) + quad) ^ rh;
  const int foff = rh * 64 + bs * 8;
  for (int kt = 0; kt < K; kt += 32) {
    async16(gA + kt, lA);
    async16(gA + (size_t)64 * K + kt, lA + 2048);
    async16(gB + kt, lB);
    async16(gB + (size_t)64 * K + kt, lB + 2048);
    __syncthreads();
    bf16x8 af[4], bfv[4];
#pragma unroll
    for (int t = 0; t < 4; t++) {
      af[t]  = *(const bf16x8*)(sA + ((wm >> 1) + t * 8) * 64 + foff);
      bfv[t] = *(const bf16x8*)(sB + ((wn >> 1) + t * 8) * 64 + foff);
    }
#pragma unroll
    for (int mt = 0; mt < 4; mt++)
#pragma unroll
      for (int nt = 0; nt < 4; nt++)
        acc[mt][nt] = MFMA_BF16(af[mt], bfv[nt], acc[mt][nt]);
    __syncthreads();
  }
#pragma unroll
  for (int mt = 0; mt < 4; mt++)
#pragma unroll
    for (int nt = 0; nt < 4; nt++) {
      int row0 = m0 + wm + mt * 16 + quad * 4;
      int col = n0 + wn + nt * 16 + l15;
#pragma unroll
      for (int r = 0; r < 4; r++)
        C[(size_t)(row0 + r) * N + col] = acc[mt][nt][r];
    }
}

// ---------------------------------------------------------------------------
// GEMM1: m201-style 8-phase (NO sched_barrier pins). 256x256 tile, BK=64,
// 512 thr / 8 waves (2Mx4N), per-wave 128x64. LDS: 2 buffers x {A0,A1,B0,B1}
// half-tiles (16KB each) = 128 KiB.
//
// Per 2 K-tiles, 8 quadrant phases:
//  Ph1 rd A(m0-3)+B(n0-1)[12] | stg b1A0 | lgkm8 | bar|lgkm0|MFMA|bar
//  Ph2 rd B(n2-3)[4]          | stg b1A1 |         bar|lgkm0|MFMA|bar
//  Ph3 rd A(m4-7)[8]          | stg b0B0'|         bar|lgkm0|MFMA|bar
//  Ph4 [0]                    | stg b0B1'| vmcnt4| bar|lgkm0|MFMA|bar
//  Ph5-8: same on buf1, staging b0A0'/b0A1'/b1B0'/b1B1', vmcnt4 @Ph8.
// vmcnt(4) retires all 4 half-tiles of the buffer read next phase; 2 newest
// half-tiles stay in flight across barriers. Drain 0 only at the tail.
__global__ __launch_bounds__(512, 2) void k_gemm_qkvz(const bf16_t* __restrict__ A,
                                                      const bf16_t* __restrict__ BT,
                                                      bf16_t* __restrict__ qkvb,
                                                      bf16_t* __restrict__ zb,
                                                      int M, int N, int K) {
  __shared__ __align__(16) bf16_t sL[2 * 4 * 8192];   // 128 KiB
  const int tid = threadIdx.x;
  const int lane = tid & 63, w = tid >> 6;
  const int quad = lane >> 4, l15 = lane & 15;

  // XCD column map (v6, verified): XCD x owns bx in [6x,6x+6), all by.
  int id = blockIdx.y * gridDim.x + blockIdx.x;
  const int xcd = id & 7, jj = id >> 3;
  const int bx = xcd * 6 + (jj % 6), by = jj / 6;
  const int m0 = by * 256, n0 = bx * 256;
  const int wm = (w >> 2) * 128, wn = (w & 3) * 64;
  const int hA = (w >> 2);             // 0/1: A half this wave reads
  const int hB = 2 + ((w & 3) >> 1);   // 2/3: B half this wave reads
  const int brow0 = wn & 64;           // row base within B half

  f32x4 acc[8][4];
#pragma unroll
  for (int m = 0; m < 8; m++)
#pragma unroll
    for (int n = 0; n < 4; n++) { f32x4 z = {0.f, 0.f, 0.f, 0.f}; acc[m][n] = z; }

  // staging source geometry (verified): per lane row rbase(+64), phys block
  // lane&7 holding logical block (lane&7)^(row&7)  (row&7 == (lane>>3)&7).
  const int rbase = w * 8 + (lane >> 3);
  const int sq = (lane & 7) ^ ((lane >> 3) & 7);
  const bf16_t* gb[4];
  gb[0] = A + (size_t)(m0 + rbase) * K + sq * 8;
  gb[1] = A + (size_t)(m0 + 128 + rbase) * K + sq * 8;
  gb[2] = BT + (size_t)(n0 + rbase) * K + sq * 8;
  gb[3] = BT + (size_t)(n0 + 128 + rbase) * K + sq * 8;
  const size_t j64 = (size_t)64 * K;

  bf16x8 afr[4][2], bf01[2][2], bf23[2][2];
  const int NI = K >> 7;   // iterations of 2 K-tiles (16 for K=2048)

  auto stg = [&](int cb, int h, int kt) {
    const bf16_t* s = gb[h] + (size_t)kt * 64;
    bf16_t* d = sL + (cb * 4 + h) * 8192 + w * 512;
    async16(s, d);
    async16(s + j64, d + 4096);
  };
  auto ldA = [&](int cb, int mg) {
    const bf16_t* base = sL + (cb * 4 + hA) * 8192;
#pragma unroll
    for (int m = 0; m < 4; m++)
#pragma unroll
      for (int ks = 0; ks < 2; ks++)
        afr[m][ks] = *(const bf16x8*)(base + (mg * 64 + m * 16 + l15) * 64 +
                                      (((ks * 4 + quad) ^ (l15 & 7)) * 8));
  };
  auto ldB = [&](int cb, int ng, bf16x8 (&bf)[2][2]) {
    const bf16_t* base = sL + (cb * 4 + hB) * 8192;
#pragma unroll
    for (int n = 0; n < 2; n++)
#pragma unroll
      for (int ks = 0; ks < 2; ks++)
        bf[n][ks] = *(const bf16x8*)(base + (brow0 + ng * 32 + n * 16 + l15) * 64 +
                                     (((ks * 4 + quad) ^ (l15 & 7)) * 8));
  };
  auto mm = [&](int mg, int ng, bf16x8 (&bf)[2][2]) {
    __builtin_amdgcn_s_setprio(1);
#pragma unroll
    for (int m = 0; m < 4; m++)
#pragma unroll
      for (int n = 0; n < 2; n++)
#pragma unroll
        for (int ks = 0; ks < 2; ks++)
          acc[mg * 4 + m][ng * 2 + n] =
              MFMA_BF16(afr[m][ks], bf[n][ks], acc[mg * 4 + m][ng * 2 + n]);
    __builtin_amdgcn_s_setprio(0);
  };

#define PH_OPEN()                                           \
  do {                                                      \
    __builtin_amdgcn_s_barrier();                           \
    asm volatile("s_waitcnt lgkmcnt(0)" ::: "memory");      \
  } while (0)
#define PH_CLOSE()                                          \
  do {                                                      \
    __builtin_amdgcn_s_barrier();                           \
  } while (0)

  // prologue: kt0 all halves, kt1 B halves (kt1 A halves come at Ph1/Ph2 of i=0)
#pragma unroll
  for (int h = 0; h < 4; h++) stg(0, h, 0);
  stg(1, 2, 1);
  stg(1, 3, 1);
  asm volatile("s_waitcnt vmcnt(4)" ::: "memory");   // kt0 complete
  __builtin_amdgcn_s_barrier();

  for (int i = 0; i < NI; ++i) {
    const int k2 = 2 * i;
    const bool more = (i + 1 < NI);
    // ---------- buf0 : K-tile k2 ----------
    // Ph1
    ldA(0, 0); ldB(0, 0, bf01);
    stg(1, 0, k2 + 1);
    asm volatile("s_waitcnt lgkmcnt(8)" ::: "memory");
    PH_OPEN(); mm(0, 0, bf01); PH_CLOSE();
    // Ph2
    ldB(0, 1, bf23);
    stg(1, 1, k2 + 1);
    PH_OPEN(); mm(0, 1, bf23); PH_CLOSE();
    // Ph3
    ldA(0, 1);
    if (more) stg(0, 2, k2 + 2);
    PH_OPEN(); mm(1, 0, bf01); PH_CLOSE();
    // Ph4
    if (more) {
      stg(0, 3, k2 + 2);
      asm volatile("s_waitcnt vmcnt(4)" ::: "memory");
    } else {
      asm volatile("s_waitcnt vmcnt(0)" ::: "memory");
    }
    PH_OPEN(); mm(1, 1, bf23); PH_CLOSE();
    // ---------- buf1 : K-tile k2+1 ----------
    // Ph5
    ldA(1, 0); ldB(1, 0, bf01);
    if (more) stg(0, 0, k2 + 2);
    asm volatile("s_waitcnt lgkmcnt(8)" ::: "memory");
    PH_OPEN(); mm(0, 0, bf01); PH_CLOSE();
    // Ph6
    ldB(1, 1, bf23);
    if (more) stg(0, 1, k2 + 2);
    PH_OPEN(); mm(0, 1, bf23); PH_CLOSE();
    // Ph7
    ldA(1, 1);
    if (more) stg(1, 2, k2 + 3);
    PH_OPEN(); mm(1, 0, bf01); PH_CLOSE();
    // Ph8
    if (more) {
      stg(1, 3, k2 + 3);
      asm volatile("s_waitcnt vmcnt(4)" ::: "memory");
    } else {
      asm volatile("s_waitcnt vmcnt(0)" ::: "memory");
    }
    PH_OPEN(); mm(1, 1, bf23); PH_CLOSE();
  }
#undef PH_OPEN
#undef PH_CLOSE

  // epilogue: split columns into qkv (kh*512+rr) and z (kh*256+rr-512)
#pragma unroll
  for (int n = 0; n < 4; n++) {
    int c = n0 + wn + n * 16 + l15;        // 0..12287
    int kh = c / 768;
    int rr = c - kh * 768;
    bool isz = (rr >= 512);
    bf16_t* dst = isz ? zb : qkvb;
    size_t stride = isz ? 4096 : 8192;
    size_t coff = isz ? (size_t)(kh * 256 + (rr - 512)) : (size_t)(kh * 512 + rr);
#pragma unroll
    for (int m = 0; m < 8; m++) {
      int row0 = m0 + wm + m * 16 + quad * 4;
#pragma unroll
      for (int r = 0; r < 4; r++)
        dst[(size_t)(row0 + r) * stride + coff] = f2bf(acc[m][n][r]);
    }
  }
}

// ---------------------------------------------------------------------------
// ba = hs @ W_ba  ->  beta = sigmoid(b), g = -exp(A_log)*softplus(a+dt_bias)
__global__ __launch_bounds__(256) void k_ba(const float* __restrict__ hs,
                                            const float* __restrict__ Wba,
                                            const float* __restrict__ A_log,
                                            const float* __restrict__ dtb,
                                            float* __restrict__ g, float* __restrict__ beta) {
  __shared__ float sH[4][2048];
  int s0 = blockIdx.x * 32;
  int c = threadIdx.x & 63, sg = threadIdx.x >> 6;
  for (int rg = 0; rg < 8; rg++) {
    __syncthreads();
    for (int i = threadIdx.x; i < 2048; i += 256) {  // float4 units
      int r = i >> 9, kk = (i & 511) * 4;
      *(float4*)(&sH[r][kk]) = *(const float4*)(hs + (size_t)(s0 + rg * 4 + r) * 2048 + kk);
    }
    __syncthreads();
    float dot = 0.f;
    for (int kk = 0; kk < 2048; kk += 4) {
      float4 hv = *(const float4*)(&sH[sg][kk]);
      dot += hv.x * Wba[(kk + 0) * 64 + c] + hv.y * Wba[(kk + 1) * 64 + c] +
             hv.z * Wba[(kk + 2) * 64 + c] + hv.w * Wba[(kk + 3) * 64 + c];
    }
    int s = s0 + rg * 4 + sg;
    int hh = c >> 2, j = c & 3;
    if (j < 2) {
      int vh = hh * 2 + j;
      beta[s * 32 + vh] = 1.f / (1.f + __expf(-dot));
    } else {
      int vh = hh * 2 + (j - 2);
      float x = dot + dtb[vh];
      float sp = (x > 20.f) ? x : log1pf(__expf(x));
      g[s * 32 + vh] = -__expf(A_log[vh]) * sp;
    }
  }
}

// ---------------------------------------------------------------------------
// depthwise causal conv (KSZ=4) + silu; bf16 in (qkvb layout kh*512+r), bf16 out
__global__ void k_conv(const bf16_t* __restrict__ qkvb, const float* __restrict__ ck,
                       bf16_t* __restrict__ qb, bf16_t* __restrict__ kb,
                       bf16_t* __restrict__ vb) {
  int c = blockIdx.x * 256 + threadIdx.x;   // 0..8191 global conv channel
  int s0 = blockIdx.y * 128;
  int col, dstc, dstride;
  bf16_t* dst;
  float scale = 1.0f;
  if (c < 2048) {
    int hh = c >> 7, d = c & 127;
    col = hh * 512 + d; dst = qb; dstc = c; dstride = 2048;
    scale = 0.08838834764831845f;  // rsqrt(DK)
  } else if (c < 4096) {
    int cc = c - 2048, hh = cc >> 7, d = cc & 127;
    col = hh * 512 + 128 + d; dst = kb; dstc = cc; dstride = 2048;
  } else {
    int cc = c - 4096, vh = cc >> 7, d = cc & 127;
    col = (vh >> 1) * 512 + 256 + (vh & 1) * 128 + d; dst = vb; dstc = cc; dstride = 4096;
  }
  float w0 = ck[c], w1 = ck[8192 + c], w2 = ck[2 * 8192 + c], w3 = ck[3 * 8192 + c];
  float x0 = 0.f, x1 = 0.f, x2 = 0.f;
  if (s0 >= 3) {
    x0 = bf2f(qkvb[(size_t)(s0 - 3) * 8192 + col]);
    x1 = bf2f(qkvb[(size_t)(s0 - 2) * 8192 + col]);
    x2 = bf2f(qkvb[(size_t)(s0 - 1) * 8192 + col]);
  }
  for (int s = s0; s < s0 + 128; s++) {
    float x3 = bf2f(qkvb[(size_t)s * 8192 + col]);
    float y = w0 * x0 + w1 * x1 + w2 * x2 + w3 * x3;
    y = y / (1.f + __expf(-y));
    dst[(size_t)s * dstride + dstc] = f2bf(y * scale);
    x0 = x1; x1 = x2; x2 = x3;
  }
}

// ---------------------------------------------------------------------------
// phase A: per (head, chunk): L, attn=(I-L)^-1 via nilpotent squaring,
// vi = attn@(beta v) (f32), kcdn = -attn@(beta e^gc k) (bf16)
__global__ __launch_bounds__(256) void k_phaseA(const bf16_t* __restrict__ kb,
                                                const bf16_t* __restrict__ vb,
                                                const float* __restrict__ g,
                                                const float* __restrict__ beta,
                                                float* __restrict__ vi,
                                                bf16_t* __restrict__ kcdn) {
  __shared__ __align__(16) char smem[36608];
  float* sGc = (float*)smem;               // [64]
  float* sBt = (float*)(smem + 256);       // [64]
  float* sBE = (float*)(smem + 512);       // [64]
  float* sP  = (float*)(smem + 768);       // [64][68] f32 -> ends 18176
  bf16_t* sQ  = (bf16_t*)(smem + 18176);   // [64][72] -> ends 27392
  bf16_t* sQT = (bf16_t*)(smem + 27392);   // [64][72] -> ends 36608
  bf16_t* sVT = (bf16_t*)(smem + 18176);   // overlay (after squaring)
  bf16_t* sKT = (bf16_t*)(smem + 27392);   // overlay

  const int tid = threadIdx.x, lane = tid & 63, w = tid >> 6;
  const int quad = lane >> 4, l15 = lane & 15;
  const int h = blockIdx.x >> 6, ci = blockIdx.x & 63;
  const int kh = h >> 1, s0 = ci * 64;
  const int m = w * 16 + l15;

  if (tid < 64) {
    float gv = g[(size_t)(s0 + tid) * 32 + h];
    float bv = beta[(size_t)(s0 + tid) * 32 + h];
#pragma unroll
    for (int off = 1; off < 64; off <<= 1) {
      float t = __shfl_up(gv, off, 64);
      if (tid >= off) gv += t;
    }
    sGc[tid] = gv; sBt[tid] = bv; sBE[tid] = bv * __expf(gv);
  }
  __syncthreads();

  // ---- raw K@K^T (exact bf16 inputs) ----
  const bf16_t* krow = kb + (size_t)s0 * 2048 + kh * 128;
  bf16x8 ak[4];
#pragma unroll
  for (int ks = 0; ks < 4; ks++)
    ak[ks] = *(const bf16x8*)(krow + (size_t)m * 2048 + ks * 32 + quad * 8);
  f32x4 accL[4];
#pragma unroll
  for (int nt = 0; nt < 4; nt++) { f32x4 z = {0.f, 0.f, 0.f, 0.f}; accL[nt] = z; }
#pragma unroll
  for (int nt = 0; nt < 4; nt++)
#pragma unroll
    for (int ks = 0; ks < 4; ks++) {
      bf16x8 bk = *(const bf16x8*)(krow + (size_t)(nt * 16 + l15) * 2048 + ks * 32 + quad * 8);
      accL[nt] = MFMA_BF16(ak[ks], bk, accL[nt]);
    }
#pragma unroll
  for (int nt = 0; nt < 4; nt++) {
    int j = nt * 16 + l15;
#pragma unroll
    for (int r = 0; r < 4; r++) {
      int i = w * 16 + quad * 4 + r;
      float Lij = (i > j) ? (-accL[nt][r] * sBt[i] * __expf(sGc[i] - sGc[j])) : 0.f;
      sP[i * 68 + j] = ((i == j) ? 1.f : 0.f) + Lij;
      bf16_t q16 = f2bf(Lij);
      sQ[i * 72 + j] = q16;
      sQT[j * 72 + i] = q16;
    }
  }
  __syncthreads();

  // ---- attn = (I+L)(I+L^2)...(I+L^32); P holds running product ----
  for (int it = 0; it < 5; it++) {
    f32x4 accQ[4];
#pragma unroll
    for (int nt = 0; nt < 4; nt++) { f32x4 z = {0.f, 0.f, 0.f, 0.f}; accQ[nt] = z; }
    bf16x8 qa[2];
#pragma unroll
    for (int ks = 0; ks < 2; ks++)
      qa[ks] = *(const bf16x8*)(sQ + m * 72 + ks * 32 + quad * 8);
#pragma unroll
    for (int nt = 0; nt < 4; nt++)
#pragma unroll
      for (int ks = 0; ks < 2; ks++) {
        bf16x8 qv = *(const bf16x8*)(sQT + (nt * 16 + l15) * 72 + ks * 32 + quad * 8);
        accQ[nt] = MFMA_BF16(qa[ks], qv, accQ[nt]);
      }
    __syncthreads();
#pragma unroll
    for (int nt = 0; nt < 4; nt++) {
      int j = nt * 16 + l15;
#pragma unroll
      for (int r = 0; r < 4; r++) {
        int i = w * 16 + quad * 4 + r;
        bf16_t q16 = f2bf(accQ[nt][r]);
        sQ[i * 72 + j] = q16;
        sQT[j * 72 + i] = q16;
      }
    }
    __syncthreads();
    // P += P @ Q (wave owns its 16 rows -> in-place safe)
    f32x4 accP[4];
#pragma unroll
    for (int nt = 0; nt < 4; nt++) { f32x4 z = {0.f, 0.f, 0.f, 0.f}; accP[nt] = z; }
    FragPair pa[2];
#pragma unroll
    for (int ks = 0; ks < 2; ks++) {
      float v[8];
      load8(v, sP + m * 68 + ks * 32 + quad * 8);
      pa[ks] = split8(v);
    }
#pragma unroll
    for (int nt = 0; nt < 4; nt++)
#pragma unroll
      for (int ks = 0; ks < 2; ks++) {
        bf16x8 qv = *(const bf16x8*)(sQT + (nt * 16 + l15) * 72 + ks * 32 + quad * 8);
        accP[nt] = MFMA_BF16(pa[ks].hi, qv, accP[nt]);
        accP[nt] = MFMA_BF16(pa[ks].lo, qv, accP[nt]);
      }
#pragma unroll
    for (int nt = 0; nt < 4; nt++) {
      int j = nt * 16 + l15;
#pragma unroll
      for (int r = 0; r < 4; r++) {
        int i = w * 16 + quad * 4 + r;
        sP[i * 68 + j] += accP[nt][r];
      }
    }
  }

  // ---- A-operand splits: attn*beta (for vi) and attn*beta*e^gc (for kcd) ----
  FragPair paV[2], paK[2];
#pragma unroll
  for (int ks = 0; ks < 2; ks++) {
    float v[8];
    load8(v, sP + m * 68 + ks * 32 + quad * 8);
    float vv[8], vk[8];
#pragma unroll
    for (int jj = 0; jj < 8; jj++) {
      int i = ks * 32 + quad * 8 + jj;
      vv[jj] = v[jj] * sBt[i];
      vk[jj] = v[jj] * sBE[i];
    }
    paV[ks] = split8(vv);
    paK[ks] = split8(vk);
  }

  // ---- vi / kcdn in two dv halves (sVT/sKT overlay sQ/sQT) ----
  for (int hf = 0; hf < 2; hf++) {
    __syncthreads();  // prior sQT/sVT/sKT readers done before overwrite
    {
      int sidx = tid & 63, dg = tid >> 6;
      const bf16_t* vsrc = vb + (size_t)(s0 + sidx) * 4096 + h * 128 + hf * 64 + dg * 16;
      const bf16_t* ksrc = kb + (size_t)(s0 + sidx) * 2048 + kh * 128 + hf * 64 + dg * 16;
      bf16x8 v0 = *(const bf16x8*)vsrc;
      bf16x8 v1 = *(const bf16x8*)(vsrc + 8);
      bf16x8 k0 = *(const bf16x8*)ksrc;
      bf16x8 k1 = *(const bf16x8*)(ksrc + 8);
#pragma unroll
      for (int e = 0; e < 8; e++) {
        sVT[(dg * 16 + e) * 72 + sidx] = v0[e];
        sVT[(dg * 16 + 8 + e) * 72 + sidx] = v1[e];
        sKT[(dg * 16 + e) * 72 + sidx] = k0[e];
        sKT[(dg * 16 + 8 + e) * 72 + sidx] = k1[e];
      }
    }
    __syncthreads();
    f32x4 accV[4], accK[4];
#pragma unroll
    for (int nt = 0; nt < 4; nt++) {
      f32x4 z = {0.f, 0.f, 0.f, 0.f};
      accV[nt] = z; accK[nt] = z;
    }
#pragma unroll
    for (int nt = 0; nt < 4; nt++)
#pragma unroll
      for (int ks = 0; ks < 2; ks++) {
        bf16x8 bv = *(const bf16x8*)(sVT + (nt * 16 + l15) * 72 + ks * 32 + quad * 8);
        accV[nt] = MFMA_BF16(paV[ks].hi, bv, accV[nt]);
        accV[nt] = MFMA_BF16(paV[ks].lo, bv, accV[nt]);
        bf16x8 bk = *(const bf16x8*)(sKT + (nt * 16 + l15) * 72 + ks * 32 + quad * 8);
        accK[nt] = MFMA_BF16(paK[ks].hi, bk, accK[nt]);
        accK[nt] = MFMA_BF16(paK[ks].lo, bk, accK[nt]);
      }
#pragma unroll
    for (int nt = 0; nt < 4; nt++) {
      int col = hf * 64 + nt * 16 + l15;
#pragma unroll
      for (int r = 0; r < 4; r++) {
        int row = w * 16 + quad * 4 + r;
        size_t o = ((size_t)h * 4096 + s0 + row) * 128 + col;
        vi[o] = accV[nt][r];
        kcdn[o] = f2bf(-accK[nt][r]);
      }
    }
  }
}

// ---------------------------------------------------------------------------
// phase B: sequential 64-chunk scan. grid = 32 heads x 8 col-groups (16 dv).
__global__ __launch_bounds__(256) void k_phaseB(const bf16_t* __restrict__ qb,
                                                const bf16_t* __restrict__ kbT,
                                                const float* __restrict__ g,
                                                const float* __restrict__ vi,
                                                const bf16_t* __restrict__ kcdn,
                                                bf16_t* __restrict__ vnT,
                                                bf16_t* __restrict__ outp) {
  __shared__ __align__(16) char smem[13312];
  float* sGc2 = (float*)smem;                 // [2][64] -> 512
  unsigned* sSTp = (unsigned*)(smem + 512);   // [16][132] -> ends 8960
  unsigned* sVTp = (unsigned*)(smem + 8960);  // [16][68] -> ends 13312
  const int tid = threadIdx.x, lane = tid & 63, w = tid >> 6;
  const int quad = lane >> 4, l15 = lane & 15;
  const int h = blockIdx.x >> 3, cg = blockIdx.x & 7;
  const int kh = h >> 1, col0 = cg * 16;
  const int m = w * 16 + l15;

  for (int i = tid; i < 16 * 132; i += 256) sSTp[i] = 0u;
  if (tid < 64) {
    float gv = g[(size_t)tid * 32 + h];
#pragma unroll
    for (int off = 1; off < 64; off <<= 1) {
      float t = __shfl_up(gv, off, 64);
      if (tid >= off) gv += t;
    }
    sGc2[tid] = gv;
  }
  __syncthreads();

  for (int ci = 0; ci < 64; ci++) {
    const int s0 = ci * 64;
    const float* sGc = sGc2 + (ci & 1) * 64;

    // per-chunk global fragments (state-independent; overlap with ds_reads)
    const bf16_t* kcrow = kcdn + ((size_t)h * 4096 + s0 + m) * 128;
    const bf16_t* qrow = qb + (size_t)(s0 + m) * 2048 + kh * 128;
    bf16x8 a1[4], a2[4], kT[2][2];
#pragma unroll
    for (int d = 0; d < 4; d++) {
      a1[d] = *(const bf16x8*)(kcrow + d * 32 + quad * 8);
      a2[d] = *(const bf16x8*)(qrow + d * 32 + quad * 8);
    }
#pragma unroll
    for (int mi = 0; mi < 2; mi++)
#pragma unroll
      for (int ks = 0; ks < 2; ks++)
        kT[mi][ks] = *(const bf16x8*)(kbT + ((size_t)(kh * 64 + ci) * 128 +
                                             w * 32 + mi * 16 + l15) * 64 + ks * 32 + quad * 8);
    const int colg = col0 + l15;
    size_t vbase = ((size_t)h * 4096 + s0 + w * 16 + quad * 4) * 128 + colg;
    f32x4 accV = {vi[vbase], vi[vbase + 128], vi[vbase + 256], vi[vbase + 384]};
    f32x4 accO = {0.f, 0.f, 0.f, 0.f};
#pragma unroll
    for (int d = 0; d < 4; d++) {
      unsigned u[8];
      load8u(u, sSTp + l15 * 132 + d * 32 + quad * 8);
      FragPair B = unpack8(u);
      accV = MFMA_BF16(a1[d], B.hi, accV);
      accV = MFMA_BF16(a1[d], B.lo, accV);
      accO = MFMA_BF16(a2[d], B.hi, accO);
      accO = MFMA_BF16(a2[d], B.lo, accO);
    }
    const float gl = sGc[63];
    {
      bf16_t* vout = vnT + ((size_t)(h * 64 + ci) * 128 + colg) * 64 + w * 16 + quad * 4;
      bf16_t* oout = outp + vbase;
      ushort4 vv;
      unsigned pk[4];
      unsigned short vb_[4];
#pragma unroll
      for (int r = 0; r < 4; r++) {
        float gr = sGc[w * 16 + quad * 4 + r];
        oout[(size_t)r * 128] = f2bf(accO[r] * __expf(gr));
        vb_[r] = __builtin_bit_cast(unsigned short, f2bf(accV[r]));
        pk[r] = packhl(accV[r] * __expf(gl - gr));  // fold decay into v_new
      }
      vv.x = vb_[0]; vv.y = vb_[1]; vv.z = vb_[2]; vv.w = vb_[3];
      *(ushort4*)vout = vv;
      uint4 pv; pv.x = pk[0]; pv.y = pk[1]; pv.z = pk[2]; pv.w = pk[3];
      *(uint4*)(sVTp + l15 * 68 + w * 16 + quad * 4) = pv;
    }
    __syncthreads();  // state reads done + sVTp visible

    // state = state*e^gl + kT @ (decayed v_new)
    f32x4 accD[2];
#pragma unroll
    for (int mi = 0; mi < 2; mi++) { f32x4 z = {0.f, 0.f, 0.f, 0.f}; accD[mi] = z; }
#pragma unroll
    for (int ks = 0; ks < 2; ks++) {
      unsigned u[8];
      load8u(u, sVTp + l15 * 68 + ks * 32 + quad * 8);
      FragPair Bv = unpack8(u);
#pragma unroll
      for (int mi = 0; mi < 2; mi++) {
        accD[mi] = MFMA_BF16(kT[mi][ks], Bv.hi, accD[mi]);
        accD[mi] = MFMA_BF16(kT[mi][ks], Bv.lo, accD[mi]);
      }
    }
    float egl = __expf(gl);
#pragma unroll
    for (int mi = 0; mi < 2; mi++) {
      int row0 = w * 32 + mi * 16 + quad * 4;
      unsigned* ps = sSTp + l15 * 132 + row0;
      uint4 old4 = *(uint4*)ps;
      uint4 nu;
      nu.x = packhl(upk(old4.x) * egl + accD[mi][0]);
      nu.y = packhl(upk(old4.y) * egl + accD[mi][1]);
      nu.z = packhl(upk(old4.z) * egl + accD[mi][2]);
      nu.w = packhl(upk(old4.w) * egl + accD[mi][3]);
      *(uint4*)ps = nu;
    }
    // next chunk's gcum into the other sGc buffer (race-free: other half)
    if (ci + 1 < 64 && tid < 64) {
      float gv = g[(size_t)((ci + 1) * 64 + tid) * 32 + h];
#pragma unroll
      for (int off = 1; off < 64; off <<= 1) {
        float t = __shfl_up(gv, off, 64);
        if (tid >= off) gv += t;
      }
      sGc2[((ci + 1) & 1) * 64 + tid] = gv;
    }
    __syncthreads();
  }
}

// ---------------------------------------------------------------------------
// phase C: a = tril(q@k^T * decay); out = outp + a @ v_new; gated RMSNorm -> xf bf16
__global__ __launch_bounds__(256) void k_phaseC(const bf16_t* __restrict__ qb,
                                                const bf16_t* __restrict__ kb,
                                                const float* __restrict__ g,
                                                const bf16_t* __restrict__ vnT,
                                                const bf16_t* __restrict__ outp,
                                                const bf16_t* __restrict__ zb,
                                                const float* __restrict__ nw,
                                                bf16_t* __restrict__ xf) {
  __shared__ __align__(16) char smem[17664];
  float* sGc = (float*)smem;                 // [64]
  unsigned* sAp = (unsigned*)(smem + 256);   // [64][68] hi/lo packed
  const int tid = threadIdx.x, lane = tid & 63, w = tid >> 6;
  const int quad = lane >> 4, l15 = lane & 15;
  const int h = blockIdx.x >> 6, ci = blockIdx.x & 63;
  const int kh = h >> 1, s0 = ci * 64;
  const int m = w * 16 + l15;

  if (tid < 64) {
    float gv = g[(size_t)(s0 + tid) * 32 + h];
#pragma unroll
    for (int off = 1; off < 64; off <<= 1) {
      float t = __shfl_up(gv, off, 64);
      if (tid >= off) gv += t;
    }
    sGc[tid] = gv;
  }
  __syncthreads();

  const bf16_t* qrow = qb + (size_t)s0 * 2048 + kh * 128;
  const bf16_t* krow = kb + (size_t)s0 * 2048 + kh * 128;
  bf16x8 aq[4];
#pragma unroll
  for (int ks = 0; ks < 4; ks++)
    aq[ks] = *(const bf16x8*)(qrow + (size_t)m * 2048 + ks * 32 + quad * 8);
  f32x4 accA[4];
#pragma unroll
  for (int nt = 0; nt < 4; nt++) { f32x4 z = {0.f, 0.f, 0.f, 0.f}; accA[nt] = z; }
#pragma unroll
  for (int nt = 0; nt < 4; nt++)
#pragma unroll
    for (int ks = 0; ks < 4; ks++) {
      bf16x8 bk = *(const bf16x8*)(krow + (size_t)(nt * 16 + l15) * 2048 + ks * 32 + quad * 8);
      accA[nt] = MFMA_BF16(aq[ks], bk, accA[nt]);
    }
#pragma unroll
  for (int nt = 0; nt < 4; nt++) {
    int j = nt * 16 + l15;
#pragma unroll
    for (int r = 0; r < 4; r++) {
      int i = w * 16 + quad * 4 + r;
      float a = (i >= j) ? accA[nt][r] * __expf(sGc[i] - sGc[j]) : 0.f;
      sAp[i * 68 + j] = packhl(a);
    }
  }
  __syncthreads();

  FragPair Aa[2];
#pragma unroll
  for (int ks = 0; ks < 2; ks++) {
    unsigned u[8];
    load8u(u, sAp + m * 68 + ks * 32 + quad * 8);
    Aa[ks] = unpack8(u);
  }
  f32x4 accO[8];
#pragma unroll
  for (int nt = 0; nt < 8; nt++) {
    size_t base = ((size_t)h * 4096 + s0 + w * 16 + quad * 4) * 128 + nt * 16 + l15;
    f32x4 z;
    z[0] = bf2f(outp[base]); z[1] = bf2f(outp[base + 128]);
    z[2] = bf2f(outp[base + 256]); z[3] = bf2f(outp[base + 384]);
    accO[nt] = z;
  }
#pragma unroll
  for (int nt = 0; nt < 8; nt++)
#pragma unroll
    for (int ks = 0; ks < 2; ks++) {
      bf16x8 bv = *(const bf16x8*)(vnT + ((size_t)(h * 64 + ci) * 128 + nt * 16 + l15) * 64 +
                                   ks * 32 + quad * 8);
      accO[nt] = MFMA_BF16(Aa[ks].hi, bv, accO[nt]);
      accO[nt] = MFMA_BF16(Aa[ks].lo, bv, accO[nt]);
    }

  // gated RMSNorm: xf = core*silu(z); xf *= rsqrt(mean(xf^2)+eps)*norm_w
  float xv[8][4];
  float ss[4] = {0.f, 0.f, 0.f, 0.f};
#pragma unroll
  for (int nt = 0; nt < 8; nt++) {
    int dv = nt * 16 + l15;
#pragma unroll
    for (int r = 0; r < 4; r++) {
      int s = s0 + w * 16 + quad * 4 + r;
      float z = bf2f(zb[(size_t)s * 4096 + h * 128 + dv]);
      float gate = z / (1.f + __expf(-z));
      float val = accO[nt][r] * gate;
      xv[nt][r] = val;
      ss[r] += val * val;
    }
  }
#pragma unroll
  for (int off = 1; off < 16; off <<= 1) {
#pragma unroll
    for (int r = 0; r < 4; r++) ss[r] += __shfl_xor(ss[r], off, 64);
  }
  float rs[4];
#pragma unroll
  for (int r = 0; r < 4; r++) rs[r] = rsqrtf(ss[r] * (1.f / 128.f) + 1e-6f);
#pragma unroll
  for (int nt = 0; nt < 8; nt++) {
    int dv = nt * 16 + l15;
    float nwv = nw[dv];
#pragma unroll
    for (int r = 0; r < 4; r++) {
      int s = s0 + w * 16 + quad * 4 + r;
      xf[(size_t)s * 4096 + h * 128 + dv] = f2bf(xv[nt][r] * rs[r] * nwv);
    }
  }
}

// ---------------------------------------------------------------------------
extern "C" void kernel_launch(void* const* d_in, const int* in_sizes, int n_in,
                              void* d_out, int out_size, void* d_ws, size_t ws_size,
                              hipStream_t stream) {
  const float* hs = (const float*)d_in[0];
  const float* Wqkvz = (const float*)d_in[1];
  const float* Wba = (const float*)d_in[2];
  const float* convk = (const float*)d_in[3];
  const float* A_log = (const float*)d_in[4];
  const float* dtb = (const float*)d_in[5];
  const float* nw = (const float*)d_in[6];
  const float* Wout = (const float*)d_in[7];
  float* out = (float*)d_out;
  char* ws = (char*)d_ws;

  // Arena: 252,706,816 B with static aliasing.
  const size_t NEED = 252706816u;
  if (ws_size < NEED) return;  // diagnostic: absmax==max|ref| => ws too small

  bf16_t* hsbf = (bf16_t*)(ws + 0);              // 16.78 MB [t1-t2]
  bf16_t* wqkT = (bf16_t*)(ws + 16777216);       // 50.33 MB [t1-t2]
  bf16_t* qb   = (bf16_t*)(ws + 0);              // 16.78 MB [t4-t7] (over hsbf)
  bf16_t* kb   = (bf16_t*)(ws + 16777216);       // 16.78 MB [t4-t7] (over wqkT)
  bf16_t* vb   = (bf16_t*)(ws + 33554432);       // 33.55 MB [t4-t5] (over wqkT)
  bf16_t* vnT  = (bf16_t*)(ws + 33554432);       // 33.55 MB [t6-t7] (over vb)
  bf16_t* qkvb = (bf16_t*)(ws + 67108864);       // 67.11 MB [t2-t4]
  float*  vi   = (float*)(ws + 67108864);        // 67.11 MB [t5-t6] (over qkvb)
  bf16_t* xf   = (bf16_t*)(ws + 67108864);       // 33.55 MB [t7-t9] (over vi)
  bf16_t* zb   = (bf16_t*)(ws + 134217728);      // 33.55 MB [t2-t7]
  float*  gbuf = (float*)(ws + 167772160);       // 0.52 MB
  float*  bbuf = (float*)(ws + 168296448);       // 0.52 MB
  bf16_t* kcdn = (bf16_t*)(ws + 168820736);      // 33.55 MB [t5-t6]
  bf16_t* woutT= (bf16_t*)(ws + 168820736);      // 16.78 MB [t8-t9] (over kcdn)
  bf16_t* outp = (bf16_t*)(ws + 202375168);      // 33.55 MB [t6-t7]
  bf16_t* kbT  = (bf16_t*)(ws + 235929600);      // 16.78 MB [t4.5-t6] -> ends 252,706,816

  k_cvt<<<8192, 256, 0, stream>>>(hs, hsbf, 4096 * 2048);                      // t1
  k_transpose_cvt<<<dim3(192, 32), 256, 0, stream>>>(Wqkvz, wqkT, 2048, 12288);
  k_gemm_qkvz<<<dim3(48, 16), 512, 0, stream>>>(hsbf, wqkT, qkvb, zb,          // t2
                                                4096, 12288, 2048);
  k_ba<<<128, 256, 0, stream>>>(hs, Wba, A_log, dtb, gbuf, bbuf);              // t3
  k_conv<<<dim3(32, 32), 256, 0, stream>>>(qkvb, convk, qb, kb, vb);           // t4
  k_ktrans<<<1024, 256, 0, stream>>>(kb, kbT);                                 // t4.5
  k_phaseA<<<2048, 256, 0, stream>>>(kb, vb, gbuf, bbuf, vi, kcdn);            // t5
  k_phaseB<<<256, 256, 0, stream>>>(qb, kbT, gbuf, vi, kcdn, vnT, outp);       // t6
  k_phaseC<<<2048, 256, 0, stream>>>(qb, kb, gbuf, vnT, outp, zb, nw, xf);     // t7
  k_transpose_cvt<<<dim3(32, 64), 256, 0, stream>>>(Wout, woutT, 4096, 2048);  // t8
  k_gemm<<<dim3(16, 32), 256, 0, stream>>>(xf, woutT, out, 4096, 2048, 4096);  // t9
}

// Round 7
// 1021.239 us; speedup vs baseline: 1.2387x; 1.0092x over previous
//
#include <hip/hip_runtime.h>

// ---------------------------------------------------------------------------
// Qwen3Next GatedDeltaNet forward, MI355X/gfx950. v10:
//  - k_gemm_qkvz: overlap via compiler counted-lgkm. Phase = {ds_reads
//    (data-dep'd into MFMAs, NO wholesale lgkm0) | stg 1 half-tile | 16 MFMA
//    | [vmcnt(4)@Ph4/Ph8 after MFMA] | ONE s_barrier}. 8 barriers/iter
//    (was 16). First MFMA starts when first read lands; read service hides
//    under MFMA; vmcnt wait overlaps MFMA. WAR chain re-derived for
//    1-barrier phases (within-phase data deps retire reads before each
//    wave's barrier); publish edge = vmcnt(4) "memory" asm + barrier.
//  - XCD column map kept (FETCH 410->148 MB verified in v6).
// ---------------------------------------------------------------------------

typedef __attribute__((ext_vector_type(8))) __bf16 bf16x8;
typedef __attribute__((ext_vector_type(4))) float f32x4;
typedef __bf16 bf16_t;

#define MFMA_BF16(A, B, C) __builtin_amdgcn_mfma_f32_16x16x32_bf16((A), (B), (C), 0, 0, 0)

__device__ __forceinline__ void async16(const bf16_t* g, bf16_t* l) {
  __builtin_amdgcn_global_load_lds(
      (const __attribute__((address_space(1))) unsigned*)g,
      (__attribute__((address_space(3))) unsigned*)l, 16, 0, 0);
}

__device__ __forceinline__ bf16_t f2bf(float x) {
  unsigned u = __builtin_bit_cast(unsigned, x);
  unsigned r = u + 0x7fffu + ((u >> 16) & 1u);
  unsigned short s = (unsigned short)(r >> 16);
  return __builtin_bit_cast(bf16_t, s);
}
__device__ __forceinline__ float bf2f(bf16_t b) {
  unsigned short s = __builtin_bit_cast(unsigned short, b);
  unsigned u = ((unsigned)s) << 16;
  return __builtin_bit_cast(float, u);
}
__device__ __forceinline__ unsigned packhl(float x) {
  bf16_t h = f2bf(x);
  bf16_t l = f2bf(x - bf2f(h));
  return (((unsigned)__builtin_bit_cast(unsigned short, h)) << 16) |
         (unsigned)__builtin_bit_cast(unsigned short, l);
}
__device__ __forceinline__ float upk(unsigned u) {
  return __builtin_bit_cast(float, u & 0xffff0000u) +
         __builtin_bit_cast(float, u << 16);
}

struct FragPair { bf16x8 hi, lo; };

__device__ __forceinline__ void load8(float v[8], const float* p) {
  float4 a = *(const float4*)p;
  float4 b = *(const float4*)(p + 4);
  v[0] = a.x; v[1] = a.y; v[2] = a.z; v[3] = a.w;
  v[4] = b.x; v[5] = b.y; v[6] = b.z; v[7] = b.w;
}
__device__ __forceinline__ void load8u(unsigned v[8], const unsigned* p) {
  uint4 a = *(const uint4*)p;
  uint4 b = *(const uint4*)(p + 4);
  v[0] = a.x; v[1] = a.y; v[2] = a.z; v[3] = a.w;
  v[4] = b.x; v[5] = b.y; v[6] = b.z; v[7] = b.w;
}
__device__ __forceinline__ FragPair split8(const float v[8]) {
  FragPair f;
#pragma unroll
  for (int j = 0; j < 8; j++) {
    bf16_t h = f2bf(v[j]);
    f.hi[j] = h;
    f.lo[j] = f2bf(v[j] - bf2f(h));
  }
  return f;
}
__device__ __forceinline__ FragPair unpack8(const unsigned v[8]) {
  FragPair f;
#pragma unroll
  for (int j = 0; j < 8; j++) {
    f.hi[j] = __builtin_bit_cast(bf16_t, (unsigned short)(v[j] >> 16));
    f.lo[j] = __builtin_bit_cast(bf16_t, (unsigned short)(v[j] & 0xffffu));
  }
  return f;
}

// ---------------------------------------------------------------------------
// elementwise f32 -> bf16
__global__ void k_cvt(const float* __restrict__ in, bf16_t* __restrict__ out, int n) {
  int i = (blockIdx.x * 256 + threadIdx.x) * 4;
  if (i + 3 < n) {
    float4 v = *(const float4*)(in + i);
    out[i + 0] = f2bf(v.x); out[i + 1] = f2bf(v.y);
    out[i + 2] = f2bf(v.z); out[i + 3] = f2bf(v.w);
  }
}

// transpose [K][N] f32 -> [N][K] bf16
__global__ void k_transpose_cvt(const float* __restrict__ in, bf16_t* __restrict__ out,
                                int K, int N) {
  __shared__ bf16_t tile[64 * 65];
  int n0 = blockIdx.x * 64, k0 = blockIdx.y * 64;
  int c = threadIdx.x & 63, rg = threadIdx.x >> 6;
#pragma unroll
  for (int rr = 0; rr < 16; rr++) {
    int r = rr * 4 + rg;
    tile[c * 65 + r] = f2bf(in[(size_t)(k0 + r) * N + n0 + c]);
  }
  __syncthreads();
#pragma unroll
  for (int rr = 0; rr < 16; rr++) {
    int r = rr * 4 + rg;
    out[(size_t)(n0 + r) * K + k0 + c] = tile[r * 65 + c];
  }
}

// ---------------------------------------------------------------------------
// per-chunk k transpose: kb[s][2048] -> kbT[kh*64+ci][dk=128][s=64] bf16
__global__ void k_ktrans(const bf16_t* __restrict__ kb, bf16_t* __restrict__ kbT) {
  __shared__ __align__(16) bf16_t t[128][72];
  int kh = blockIdx.x >> 6, ci = blockIdx.x & 63, s0 = ci * 64;
  int s = threadIdx.x & 63, dg = threadIdx.x >> 6;
  const bf16_t* src = kb + (size_t)(s0 + s) * 2048 + kh * 128 + dg * 32;
#pragma unroll
  for (int j = 0; j < 4; j++) {
    bf16x8 v = *(const bf16x8*)(src + j * 8);
#pragma unroll
    for (int e = 0; e < 8; e++) t[dg * 32 + j * 8 + e][s] = v[e];
  }
  __syncthreads();
  int d = threadIdx.x >> 1, sh = (threadIdx.x & 1) * 32;
  bf16_t* dst = kbT + ((size_t)blockIdx.x * 128 + d) * 64 + sh;
#pragma unroll
  for (int j = 0; j < 4; j++)
    *(bf16x8*)(dst + j * 8) = *(const bf16x8*)(&t[d][sh + j * 8]);
}

// ---------------------------------------------------------------------------
// Old-structure swizzled GEMM (kept for t9: C[M,N]=A*BT^T fp32 out, 128^2 tile)
__global__ __launch_bounds__(256) void k_gemm(const bf16_t* __restrict__ A,
                                              const bf16_t* __restrict__ BT,
                                              float* __restrict__ C, int M, int N, int K) {
  __shared__ __align__(16) bf16_t sA[128 * 32];
  __shared__ __align__(16) bf16_t sB[128 * 32];
  const int tid = threadIdx.x;
  const int lane = tid & 63, w = tid >> 6;
  const int quad = lane >> 4, l15 = lane & 15;
  const int m0 = blockIdx.y * 128, n0 = blockIdx.x * 128;
  const int wm = (w >> 1) * 64, wn = (w & 1) * 64;
  f32x4 acc[4][4];
#pragma unroll
  for (int a = 0; a < 4; a++)
#pragma unroll
    for (int b = 0; b < 4; b++) { f32x4 z = {0.f, 0.f, 0.f, 0.f}; acc[a][b] = z; }
  const int sb = (lane & 7) ^ ((lane >> 3) & 7);
  const int srow = ((tid >> 3) << 1) + (sb >> 2);   // 0..63
  const int scol = (sb & 3) * 8;
  const bf16_t* gA = A + (size_t)(m0 + srow) * K + scol;
  const bf16_t* gB = BT + (size_t)(n0 + srow) * K + scol;
  bf16_t* lA = sA + w * 512;   // wave-uniform base; HW adds lane*16B
  bf16_t* lB = sB + w * 512;
  const int rh = l15 >> 1;
  const int bs = (((l15 & 1) << 2) + quad) ^ rh;
  const int foff = rh * 64 + bs * 8;
  for (int kt = 0; kt < K; kt += 32) {
    async16(gA + kt, lA);
    async16(gA + (size_t)64 * K + kt, lA + 2048);
    async16(gB + kt, lB);
    async16(gB + (size_t)64 * K + kt, lB + 2048);
    __syncthreads();
    bf16x8 af[4], bfv[4];
#pragma unroll
    for (int t = 0; t < 4; t++) {
      af[t]  = *(const bf16x8*)(sA + ((wm >> 1) + t * 8) * 64 + foff);
      bfv[t] = *(const bf16x8*)(sB + ((wn >> 1) + t * 8) * 64 + foff);
    }
#pragma unroll
    for (int mt = 0; mt < 4; mt++)
#pragma unroll
      for (int nt = 0; nt < 4; nt++)
        acc[mt][nt] = MFMA_BF16(af[mt], bfv[nt], acc[mt][nt]);
    __syncthreads();
  }
#pragma unroll
  for (int mt = 0; mt < 4; mt++)
#pragma unroll
    for (int nt = 0; nt < 4; nt++) {
      int row0 = m0 + wm + mt * 16 + quad * 4;
      int col = n0 + wn + nt * 16 + l15;
#pragma unroll
      for (int r = 0; r < 4; r++)
        C[(size_t)(row0 + r) * N + col] = acc[mt][nt][r];
    }
}

// ---------------------------------------------------------------------------
// GEMM1: 8-phase, compiler-interleaved reads. 256x256 tile, BK=64, 512 thr /
// 8 waves (2Mx4N), per-wave 128x64. LDS: 2 buffers x {A0,A1,B0,B1} (16KB) =
// 128 KiB.
//
// Phase p = { ds_reads for THIS phase's new frags (consumed by MFMAs via
// data deps -> compiler emits counted lgkmcnt) | stg 1 half-tile | 16 MFMA |
// [vmcnt(4) @Ph4/Ph8 after MFMA] | s_barrier }.
// Reads/phase: Ph1 A(m0-3)+B(n0-1)=12, Ph2 B(n2-3)=4, Ph3 A(m4-7)=8, Ph4 0.
// Stages: Ph1 b1A0, Ph2 b1A1, Ph3 b0B0', Ph4 b0B1' (vmcnt4), Ph5-8 mirror.
// vmcnt(4)@Ph4 retires all of buf1 (published by the Ph4 barrier); the 2
// newest half-tiles stay in flight. Drain 0 only at tail. WAR: every stg
// target's last reader consumed its reads (data dep) >=1 barrier earlier.
__global__ __launch_bounds__(512, 2) void k_gemm_qkvz(const bf16_t* __restrict__ A,
                                                      const bf16_t* __restrict__ BT,
                                                      bf16_t* __restrict__ qkvb,
                                                      bf16_t* __restrict__ zb,
                                                      int M, int N, int K) {
  __shared__ __align__(16) bf16_t sL[2 * 4 * 8192];   // 128 KiB
  const int tid = threadIdx.x;
  const int lane = tid & 63, w = tid >> 6;
  const int quad = lane >> 4, l15 = lane & 15;

  // XCD column map (v6, verified): XCD x owns bx in [6x,6x+6), all by.
  int id = blockIdx.y * gridDim.x + blockIdx.x;
  const int xcd = id & 7, jj = id >> 3;
  const int bx = xcd * 6 + (jj % 6), by = jj / 6;
  const int m0 = by * 256, n0 = bx * 256;
  const int wm = (w >> 2) * 128, wn = (w & 3) * 64;
  const int hA = (w >> 2);             // 0/1: A half this wave reads
  const int hB = 2 + ((w & 3) >> 1);   // 2/3: B half this wave reads
  const int brow0 = wn & 64;           // row base within B half

  f32x4 acc[8][4];
#pragma unroll
  for (int m = 0; m < 8; m++)
#pragma unroll
    for (int n = 0; n < 4; n++) { f32x4 z = {0.f, 0.f, 0.f, 0.f}; acc[m][n] = z; }

  // staging source geometry (verified): per lane row rbase(+64), phys block
  // lane&7 holding logical block (lane&7)^(row&7)  (row&7 == (lane>>3)&7).
  const int rbase = w * 8 + (lane >> 3);
  const int sq = (lane & 7) ^ ((lane >> 3) & 7);
  const bf16_t* gb[4];
  gb[0] = A + (size_t)(m0 + rbase) * K + sq * 8;
  gb[1] = A + (size_t)(m0 + 128 + rbase) * K + sq * 8;
  gb[2] = BT + (size_t)(n0 + rbase) * K + sq * 8;
  gb[3] = BT + (size_t)(n0 + 128 + rbase) * K + sq * 8;
  const size_t j64 = (size_t)64 * K;

  bf16x8 afr[4][2], bf01[2][2], bf23[2][2];
  const int NI = K >> 7;   // iterations of 2 K-tiles (16 for K=2048)

  auto stg = [&](int cb, int h, int kt) {
    const bf16_t* s = gb[h] + (size_t)kt * 64;
    bf16_t* d = sL + (cb * 4 + h) * 8192 + w * 512;
    async16(s, d);
    async16(s + j64, d + 4096);
  };
  auto ldA = [&](int cb, int mg) {
    const bf16_t* base = sL + (cb * 4 + hA) * 8192;
#pragma unroll
    for (int m = 0; m < 4; m++)
#pragma unroll
      for (int ks = 0; ks < 2; ks++)
        afr[m][ks] = *(const bf16x8*)(base + (mg * 64 + m * 16 + l15) * 64 +
                                      (((ks * 4 + quad) ^ (l15 & 7)) * 8));
  };
  auto ldB = [&](int cb, int ng, bf16x8 (&bf)[2][2]) {
    const bf16_t* base = sL + (cb * 4 + hB) * 8192;
#pragma unroll
    for (int n = 0; n < 2; n++)
#pragma unroll
      for (int ks = 0; ks < 2; ks++)
        bf[n][ks] = *(const bf16x8*)(base + (brow0 + ng * 32 + n * 16 + l15) * 64 +
                                     (((ks * 4 + quad) ^ (l15 & 7)) * 8));
  };
  auto mm = [&](int mg, int ng, bf16x8 (&bf)[2][2]) {
    __builtin_amdgcn_s_setprio(1);
#pragma unroll
    for (int m = 0; m < 4; m++)
#pragma unroll
      for (int n = 0; n < 2; n++)
#pragma unroll
        for (int ks = 0; ks < 2; ks++)
          acc[mg * 4 + m][ng * 2 + n] =
              MFMA_BF16(afr[m][ks], bf[n][ks], acc[mg * 4 + m][ng * 2 + n]);
    __builtin_amdgcn_s_setprio(0);
  };

  // prologue: kt0 all halves, kt1 B halves (kt1 A halves staged at Ph1/Ph2)
#pragma unroll
  for (int h = 0; h < 4; h++) stg(0, h, 0);
  stg(1, 2, 1);
  stg(1, 3, 1);
  asm volatile("s_waitcnt vmcnt(4)" ::: "memory");   // kt0 complete
  __builtin_amdgcn_s_barrier();

  for (int i = 0; i < NI; ++i) {
    const int k2 = 2 * i;
    const bool more = (i + 1 < NI);
    // ---------- buf0 : K-tile k2 ----------
    // Ph1: read A(m0-3)+B(n0-1) of buf0; stage b1A0; MFMA Q(m0-3,n0-1)
    ldA(0, 0); ldB(0, 0, bf01);
    stg(1, 0, k2 + 1);
    mm(0, 0, bf01);
    __builtin_amdgcn_s_barrier();
    // Ph2: read B(n2-3); stage b1A1; MFMA Q(m0-3,n2-3)
    ldB(0, 1, bf23);
    stg(1, 1, k2 + 1);
    mm(0, 1, bf23);
    __builtin_amdgcn_s_barrier();
    // Ph3: read A(m4-7); stage b0B0'; MFMA Q(m4-7,n0-1)
    ldA(0, 1);
    if (more) stg(0, 2, k2 + 2);
    mm(1, 0, bf01);
    __builtin_amdgcn_s_barrier();
    // Ph4: stage b0B1'; MFMA Q(m4-7,n2-3); publish buf1 (vmcnt under MFMA)
    if (more) stg(0, 3, k2 + 2);
    mm(1, 1, bf23);
    if (more) asm volatile("s_waitcnt vmcnt(4)" ::: "memory");
    else      asm volatile("s_waitcnt vmcnt(0)" ::: "memory");
    __builtin_amdgcn_s_barrier();
    // ---------- buf1 : K-tile k2+1 ----------
    // Ph5
    ldA(1, 0); ldB(1, 0, bf01);
    if (more) stg(0, 0, k2 + 2);
    mm(0, 0, bf01);
    __builtin_amdgcn_s_barrier();
    // Ph6
    ldB(1, 1, bf23);
    if (more) stg(0, 1, k2 + 2);
    mm(0, 1, bf23);
    __builtin_amdgcn_s_barrier();
    // Ph7
    ldA(1, 1);
    if (more) stg(1, 2, k2 + 3);
    mm(1, 0, bf01);
    __builtin_amdgcn_s_barrier();
    // Ph8: publish buf0' for next iteration
    if (more) stg(1, 3, k2 + 3);
    mm(1, 1, bf23);
    if (more) asm volatile("s_waitcnt vmcnt(4)" ::: "memory");
    else      asm volatile("s_waitcnt vmcnt(0)" ::: "memory");
    __builtin_amdgcn_s_barrier();
  }

  // epilogue: split columns into qkv (kh*512+rr) and z (kh*256+rr-512)
#pragma unroll
  for (int n = 0; n < 4; n++) {
    int c = n0 + wn + n * 16 + l15;        // 0..12287
    int kh = c / 768;
    int rr = c - kh * 768;
    bool isz = (rr >= 512);
    bf16_t* dst = isz ? zb : qkvb;
    size_t stride = isz ? 4096 : 8192;
    size_t coff = isz ? (size_t)(kh * 256 + (rr - 512)) : (size_t)(kh * 512 + rr);
#pragma unroll
    for (int m = 0; m < 8; m++) {
      int row0 = m0 + wm + m * 16 + quad * 4;
#pragma unroll
      for (int r = 0; r < 4; r++)
        dst[(size_t)(row0 + r) * stride + coff] = f2bf(acc[m][n][r]);
    }
  }
}

// ---------------------------------------------------------------------------
// ba = hs @ W_ba  ->  beta = sigmoid(b), g = -exp(A_log)*softplus(a+dt_bias)
__global__ __launch_bounds__(256) void k_ba(const float* __restrict__ hs,
                                            const float* __restrict__ Wba,
                                            const float* __restrict__ A_log,
                                            const float* __restrict__ dtb,
                                            float* __restrict__ g, float* __restrict__ beta) {
  __shared__ float sH[4][2048];
  int s0 = blockIdx.x * 32;
  int c = threadIdx.x & 63, sg = threadIdx.x >> 6;
  for (int rg = 0; rg < 8; rg++) {
    __syncthreads();
    for (int i = threadIdx.x; i < 2048; i += 256) {  // float4 units
      int r = i >> 9, kk = (i & 511) * 4;
      *(float4*)(&sH[r][kk]) = *(const float4*)(hs + (size_t)(s0 + rg * 4 + r) * 2048 + kk);
    }
    __syncthreads();
    float dot = 0.f;
    for (int kk = 0; kk < 2048; kk += 4) {
      float4 hv = *(const float4*)(&sH[sg][kk]);
      dot += hv.x * Wba[(kk + 0) * 64 + c] + hv.y * Wba[(kk + 1) * 64 + c] +
             hv.z * Wba[(kk + 2) * 64 + c] + hv.w * Wba[(kk + 3) * 64 + c];
    }
    int s = s0 + rg * 4 + sg;
    int hh = c >> 2, j = c & 3;
    if (j < 2) {
      int vh = hh * 2 + j;
      beta[s * 32 + vh] = 1.f / (1.f + __expf(-dot));
    } else {
      int vh = hh * 2 + (j - 2);
      float x = dot + dtb[vh];
      float sp = (x > 20.f) ? x : log1pf(__expf(x));
      g[s * 32 + vh] = -__expf(A_log[vh]) * sp;
    }
  }
}

// ---------------------------------------------------------------------------
// depthwise causal conv (KSZ=4) + silu; bf16 in (qkvb layout kh*512+r), bf16 out
__global__ void k_conv(const bf16_t* __restrict__ qkvb, const float* __restrict__ ck,
                       bf16_t* __restrict__ qb, bf16_t* __restrict__ kb,
                       bf16_t* __restrict__ vb) {
  int c = blockIdx.x * 256 + threadIdx.x;   // 0..8191 global conv channel
  int s0 = blockIdx.y * 128;
  int col, dstc, dstride;
  bf16_t* dst;
  float scale = 1.0f;
  if (c < 2048) {
    int hh = c >> 7, d = c & 127;
    col = hh * 512 + d; dst = qb; dstc = c; dstride = 2048;
    scale = 0.08838834764831845f;  // rsqrt(DK)
  } else if (c < 4096) {
    int cc = c - 2048, hh = cc >> 7, d = cc & 127;
    col = hh * 512 + 128 + d; dst = kb; dstc = cc; dstride = 2048;
  } else {
    int cc = c - 4096, vh = cc >> 7, d = cc & 127;
    col = (vh >> 1) * 512 + 256 + (vh & 1) * 128 + d; dst = vb; dstc = cc; dstride = 4096;
  }
  float w0 = ck[c], w1 = ck[8192 + c], w2 = ck[2 * 8192 + c], w3 = ck[3 * 8192 + c];
  float x0 = 0.f, x1 = 0.f, x2 = 0.f;
  if (s0 >= 3) {
    x0 = bf2f(qkvb[(size_t)(s0 - 3) * 8192 + col]);
    x1 = bf2f(qkvb[(size_t)(s0 - 2) * 8192 + col]);
    x2 = bf2f(qkvb[(size_t)(s0 - 1) * 8192 + col]);
  }
  for (int s = s0; s < s0 + 128; s++) {
    float x3 = bf2f(qkvb[(size_t)s * 8192 + col]);
    float y = w0 * x0 + w1 * x1 + w2 * x2 + w3 * x3;
    y = y / (1.f + __expf(-y));
    dst[(size_t)s * dstride + dstc] = f2bf(y * scale);
    x0 = x1; x1 = x2; x2 = x3;
  }
}

// ---------------------------------------------------------------------------
// phase A: per (head, chunk): L, attn=(I-L)^-1 via nilpotent squaring,
// vi = attn@(beta v) (f32), kcdn = -attn@(beta e^gc k) (bf16)
__global__ __launch_bounds__(256) void k_phaseA(const bf16_t* __restrict__ kb,
                                                const bf16_t* __restrict__ vb,
                                                const float* __restrict__ g,
                                                const float* __restrict__ beta,
                                                float* __restrict__ vi,
                                                bf16_t* __restrict__ kcdn) {
  __shared__ __align__(16) char smem[36608];
  float* sGc = (float*)smem;               // [64]
  float* sBt = (float*)(smem + 256);       // [64]
  float* sBE = (float*)(smem + 512);       // [64]
  float* sP  = (float*)(smem + 768);       // [64][68] f32 -> ends 18176
  bf16_t* sQ  = (bf16_t*)(smem + 18176);   // [64][72] -> ends 27392
  bf16_t* sQT = (bf16_t*)(smem + 27392);   // [64][72] -> ends 36608
  bf16_t* sVT = (bf16_t*)(smem + 18176);   // overlay (after squaring)
  bf16_t* sKT = (bf16_t*)(smem + 27392);   // overlay

  const int tid = threadIdx.x, lane = tid & 63, w = tid >> 6;
  const int quad = lane >> 4, l15 = lane & 15;
  const int h = blockIdx.x >> 6, ci = blockIdx.x & 63;
  const int kh = h >> 1, s0 = ci * 64;
  const int m = w * 16 + l15;

  if (tid < 64) {
    float gv = g[(size_t)(s0 + tid) * 32 + h];
    float bv = beta[(size_t)(s0 + tid) * 32 + h];
#pragma unroll
    for (int off = 1; off < 64; off <<= 1) {
      float t = __shfl_up(gv, off, 64);
      if (tid >= off) gv += t;
    }
    sGc[tid] = gv; sBt[tid] = bv; sBE[tid] = bv * __expf(gv);
  }
  __syncthreads();

  // ---- raw K@K^T (exact bf16 inputs) ----
  const bf16_t* krow = kb + (size_t)s0 * 2048 + kh * 128;
  bf16x8 ak[4];
#pragma unroll
  for (int ks = 0; ks < 4; ks++)
    ak[ks] = *(const bf16x8*)(krow + (size_t)m * 2048 + ks * 32 + quad * 8);
  f32x4 accL[4];
#pragma unroll
  for (int nt = 0; nt < 4; nt++) { f32x4 z = {0.f, 0.f, 0.f, 0.f}; accL[nt] = z; }
#pragma unroll
  for (int nt = 0; nt < 4; nt++)
#pragma unroll
    for (int ks = 0; ks < 4; ks++) {
      bf16x8 bk = *(const bf16x8*)(krow + (size_t)(nt * 16 + l15) * 2048 + ks * 32 + quad * 8);
      accL[nt] = MFMA_BF16(ak[ks], bk, accL[nt]);
    }
#pragma unroll
  for (int nt = 0; nt < 4; nt++) {
    int j = nt * 16 + l15;
#pragma unroll
    for (int r = 0; r < 4; r++) {
      int i = w * 16 + quad * 4 + r;
      float Lij = (i > j) ? (-accL[nt][r] * sBt[i] * __expf(sGc[i] - sGc[j])) : 0.f;
      sP[i * 68 + j] = ((i == j) ? 1.f : 0.f) + Lij;
      bf16_t q16 = f2bf(Lij);
      sQ[i * 72 + j] = q16;
      sQT[j * 72 + i] = q16;
    }
  }
  __syncthreads();

  // ---- attn = (I+L)(I+L^2)...(I+L^32); P holds running product ----
  for (int it = 0; it < 5; it++) {
    f32x4 accQ[4];
#pragma unroll
    for (int nt = 0; nt < 4; nt++) { f32x4 z = {0.f, 0.f, 0.f, 0.f}; accQ[nt] = z; }
    bf16x8 qa[2];
#pragma unroll
    for (int ks = 0; ks < 2; ks++)
      qa[ks] = *(const bf16x8*)(sQ + m * 72 + ks * 32 + quad * 8);
#pragma unroll
    for (int nt = 0; nt < 4; nt++)
#pragma unroll
      for (int ks = 0; ks < 2; ks++) {
        bf16x8 qv = *(const bf16x8*)(sQT + (nt * 16 + l15) * 72 + ks * 32 + quad * 8);
        accQ[nt] = MFMA_BF16(qa[ks], qv, accQ[nt]);
      }
    __syncthreads();
#pragma unroll
    for (int nt = 0; nt < 4; nt++) {
      int j = nt * 16 + l15;
#pragma unroll
      for (int r = 0; r < 4; r++) {
        int i = w * 16 + quad * 4 + r;
        bf16_t q16 = f2bf(accQ[nt][r]);
        sQ[i * 72 + j] = q16;
        sQT[j * 72 + i] = q16;
      }
    }
    __syncthreads();
    // P += P @ Q (wave owns its 16 rows -> in-place safe)
    f32x4 accP[4];
#pragma unroll
    for (int nt = 0; nt < 4; nt++) { f32x4 z = {0.f, 0.f, 0.f, 0.f}; accP[nt] = z; }
    FragPair pa[2];
#pragma unroll
    for (int ks = 0; ks < 2; ks++) {
      float v[8];
      load8(v, sP + m * 68 + ks * 32 + quad * 8);
      pa[ks] = split8(v);
    }
#pragma unroll
    for (int nt = 0; nt < 4; nt++)
#pragma unroll
      for (int ks = 0; ks < 2; ks++) {
        bf16x8 qv = *(const bf16x8*)(sQT + (nt * 16 + l15) * 72 + ks * 32 + quad * 8);
        accP[nt] = MFMA_BF16(pa[ks].hi, qv, accP[nt]);
        accP[nt] = MFMA_BF16(pa[ks].lo, qv, accP[nt]);
      }
#pragma unroll
    for (int nt = 0; nt < 4; nt++) {
      int j = nt * 16 + l15;
#pragma unroll
      for (int r = 0; r < 4; r++) {
        int i = w * 16 + quad * 4 + r;
        sP[i * 68 + j] += accP[nt][r];
      }
    }
  }

  // ---- A-operand splits: attn*beta (for vi) and attn*beta*e^gc (for kcd) ----
  FragPair paV[2], paK[2];
#pragma unroll
  for (int ks = 0; ks < 2; ks++) {
    float v[8];
    load8(v, sP + m * 68 + ks * 32 + quad * 8);
    float vv[8], vk[8];
#pragma unroll
    for (int jj = 0; jj < 8; jj++) {
      int i = ks * 32 + quad * 8 + jj;
      vv[jj] = v[jj] * sBt[i];
      vk[jj] = v[jj] * sBE[i];
    }
    paV[ks] = split8(vv);
    paK[ks] = split8(vk);
  }

  // ---- vi / kcdn in two dv halves (sVT/sKT overlay sQ/sQT) ----
  for (int hf = 0; hf < 2; hf++) {
    __syncthreads();  // prior sQT/sVT/sKT readers done before overwrite
    {
      int sidx = tid & 63, dg = tid >> 6;
      const bf16_t* vsrc = vb + (size_t)(s0 + sidx) * 4096 + h * 128 + hf * 64 + dg * 16;
      const bf16_t* ksrc = kb + (size_t)(s0 + sidx) * 2048 + kh * 128 + hf * 64 + dg * 16;
      bf16x8 v0 = *(const bf16x8*)vsrc;
      bf16x8 v1 = *(const bf16x8*)(vsrc + 8);
      bf16x8 k0 = *(const bf16x8*)ksrc;
      bf16x8 k1 = *(const bf16x8*)(ksrc + 8);
#pragma unroll
      for (int e = 0; e < 8; e++) {
        sVT[(dg * 16 + e) * 72 + sidx] = v0[e];
        sVT[(dg * 16 + 8 + e) * 72 + sidx] = v1[e];
        sKT[(dg * 16 + e) * 72 + sidx] = k0[e];
        sKT[(dg * 16 + 8 + e) * 72 + sidx] = k1[e];
      }
    }
    __syncthreads();
    f32x4 accV[4], accK[4];
#pragma unroll
    for (int nt = 0; nt < 4; nt++) {
      f32x4 z = {0.f, 0.f, 0.f, 0.f};
      accV[nt] = z; accK[nt] = z;
    }
#pragma unroll
    for (int nt = 0; nt < 4; nt++)
#pragma unroll
      for (int ks = 0; ks < 2; ks++) {
        bf16x8 bv = *(const bf16x8*)(sVT + (nt * 16 + l15) * 72 + ks * 32 + quad * 8);
        accV[nt] = MFMA_BF16(paV[ks].hi, bv, accV[nt]);
        accV[nt] = MFMA_BF16(paV[ks].lo, bv, accV[nt]);
        bf16x8 bk = *(const bf16x8*)(sKT + (nt * 16 + l15) * 72 + ks * 32 + quad * 8);
        accK[nt] = MFMA_BF16(paK[ks].hi, bk, accK[nt]);
        accK[nt] = MFMA_BF16(paK[ks].lo, bk, accK[nt]);
      }
#pragma unroll
    for (int nt = 0; nt < 4; nt++) {
      int col = hf * 64 + nt * 16 + l15;
#pragma unroll
      for (int r = 0; r < 4; r++) {
        int row = w * 16 + quad * 4 + r;
        size_t o = ((size_t)h * 4096 + s0 + row) * 128 + col;
        vi[o] = accV[nt][r];
        kcdn[o] = f2bf(-accK[nt][r]);
      }
    }
  }
}

// ---------------------------------------------------------------------------
// phase B: sequential 64-chunk scan. grid = 32 heads x 8 col-groups (16 dv).
__global__ __launch_bounds__(256) void k_phaseB(const bf16_t* __restrict__ qb,
                                                const bf16_t* __restrict__ kbT,
                                                const float* __restrict__ g,
                                                const float* __restrict__ vi,
                                                const bf16_t* __restrict__ kcdn,
                                                bf16_t* __restrict__ vnT,
                                                bf16_t* __restrict__ outp) {
  __shared__ __align__(16) char smem[13312];
  float* sGc2 = (float*)smem;                 // [2][64] -> 512
  unsigned* sSTp = (unsigned*)(smem + 512);   // [16][132] -> ends 8960
  unsigned* sVTp = (unsigned*)(smem + 8960);  // [16][68] -> ends 13312
  const int tid = threadIdx.x, lane = tid & 63, w = tid >> 6;
  const int quad = lane >> 4, l15 = lane & 15;
  const int h = blockIdx.x >> 3, cg = blockIdx.x & 7;
  const int kh = h >> 1, col0 = cg * 16;
  const int m = w * 16 + l15;

  for (int i = tid; i < 16 * 132; i += 256) sSTp[i] = 0u;
  if (tid < 64) {
    float gv = g[(size_t)tid * 32 + h];
#pragma unroll
    for (int off = 1; off < 64; off <<= 1) {
      float t = __shfl_up(gv, off, 64);
      if (tid >= off) gv += t;
    }
    sGc2[tid] = gv;
  }
  __syncthreads();

  for (int ci = 0; ci < 64; ci++) {
    const int s0 = ci * 64;
    const float* sGc = sGc2 + (ci & 1) * 64;

    // per-chunk global fragments (state-independent; overlap with ds_reads)
    const bf16_t* kcrow = kcdn + ((size_t)h * 4096 + s0 + m) * 128;
    const bf16_t* qrow = qb + (size_t)(s0 + m) * 2048 + kh * 128;
    bf16x8 a1[4], a2[4], kT[2][2];
#pragma unroll
    for (int d = 0; d < 4; d++) {
      a1[d] = *(const bf16x8*)(kcrow + d * 32 + quad * 8);
      a2[d] = *(const bf16x8*)(qrow + d * 32 + quad * 8);
    }
#pragma unroll
    for (int mi = 0; mi < 2; mi++)
#pragma unroll
      for (int ks = 0; ks < 2; ks++)
        kT[mi][ks] = *(const bf16x8*)(kbT + ((size_t)(kh * 64 + ci) * 128 +
                                             w * 32 + mi * 16 + l15) * 64 + ks * 32 + quad * 8);
    const int colg = col0 + l15;
    size_t vbase = ((size_t)h * 4096 + s0 + w * 16 + quad * 4) * 128 + colg;
    f32x4 accV = {vi[vbase], vi[vbase + 128], vi[vbase + 256], vi[vbase + 384]};
    f32x4 accO = {0.f, 0.f, 0.f, 0.f};
#pragma unroll
    for (int d = 0; d < 4; d++) {
      unsigned u[8];
      load8u(u, sSTp + l15 * 132 + d * 32 + quad * 8);
      FragPair B = unpack8(u);
      accV = MFMA_BF16(a1[d], B.hi, accV);
      accV = MFMA_BF16(a1[d], B.lo, accV);
      accO = MFMA_BF16(a2[d], B.hi, accO);
      accO = MFMA_BF16(a2[d], B.lo, accO);
    }
    const float gl = sGc[63];
    {
      bf16_t* vout = vnT + ((size_t)(h * 64 + ci) * 128 + colg) * 64 + w * 16 + quad * 4;
      bf16_t* oout = outp + vbase;
      ushort4 vv;
      unsigned pk[4];
      unsigned short vb_[4];
#pragma unroll
      for (int r = 0; r < 4; r++) {
        float gr = sGc[w * 16 + quad * 4 + r];
        oout[(size_t)r * 128] = f2bf(accO[r] * __expf(gr));
        vb_[r] = __builtin_bit_cast(unsigned short, f2bf(accV[r]));
        pk[r] = packhl(accV[r] * __expf(gl - gr));  // fold decay into v_new
      }
      vv.x = vb_[0]; vv.y = vb_[1]; vv.z = vb_[2]; vv.w = vb_[3];
      *(ushort4*)vout = vv;
      uint4 pv; pv.x = pk[0]; pv.y = pk[1]; pv.z = pk[2]; pv.w = pk[3];
      *(uint4*)(sVTp + l15 * 68 + w * 16 + quad * 4) = pv;
    }
    __syncthreads();  // state reads done + sVTp visible

    // state = state*e^gl + kT @ (decayed v_new)
    f32x4 accD[2];
#pragma unroll
    for (int mi = 0; mi < 2; mi++) { f32x4 z = {0.f, 0.f, 0.f, 0.f}; accD[mi] = z; }
#pragma unroll
    for (int ks = 0; ks < 2; ks++) {
      unsigned u[8];
      load8u(u, sVTp + l15 * 68 + ks * 32 + quad * 8);
      FragPair Bv = unpack8(u);
#pragma unroll
      for (int mi = 0; mi < 2; mi++) {
        accD[mi] = MFMA_BF16(kT[mi][ks], Bv.hi, accD[mi]);
        accD[mi] = MFMA_BF16(kT[mi][ks], Bv.lo, accD[mi]);
      }
    }
    float egl = __expf(gl);
#pragma unroll
    for (int mi = 0; mi < 2; mi++) {
      int row0 = w * 32 + mi * 16 + quad * 4;
      unsigned* ps = sSTp + l15 * 132 + row0;
      uint4 old4 = *(uint4*)ps;
      uint4 nu;
      nu.x = packhl(upk(old4.x) * egl + accD[mi][0]);
      nu.y = packhl(upk(old4.y) * egl + accD[mi][1]);
      nu.z = packhl(upk(old4.z) * egl + accD[mi][2]);
      nu.w = packhl(upk(old4.w) * egl + accD[mi][3]);
      *(uint4*)ps = nu;
    }
    // next chunk's gcum into the other sGc buffer (race-free: other half)
    if (ci + 1 < 64 && tid < 64) {
      float gv = g[(size_t)((ci + 1) * 64 + tid) * 32 + h];
#pragma unroll
      for (int off = 1; off < 64; off <<= 1) {
        float t = __shfl_up(gv, off, 64);
        if (tid >= off) gv += t;
      }
      sGc2[((ci + 1) & 1) * 64 + tid] = gv;
    }
    __syncthreads();
  }
}

// ---------------------------------------------------------------------------
// phase C: a = tril(q@k^T * decay); out = outp + a @ v_new; gated RMSNorm -> xf bf16
__global__ __launch_bounds__(256) void k_phaseC(const bf16_t* __restrict__ qb,
                                                const bf16_t* __restrict__ kb,
                                                const float* __restrict__ g,
                                                const bf16_t* __restrict__ vnT,
                                                const bf16_t* __restrict__ outp,
                                                const bf16_t* __restrict__ zb,
                                                const float* __restrict__ nw,
                                                bf16_t* __restrict__ xf) {
  __shared__ __align__(16) char smem[17664];
  float* sGc = (float*)smem;                 // [64]
  unsigned* sAp = (unsigned*)(smem + 256);   // [64][68] hi/lo packed
  const int tid = threadIdx.x, lane = tid & 63, w = tid >> 6;
  const int quad = lane >> 4, l15 = lane & 15;
  const int h = blockIdx.x >> 6, ci = blockIdx.x & 63;
  const int kh = h >> 1, s0 = ci * 64;
  const int m = w * 16 + l15;

  if (tid < 64) {
    float gv = g[(size_t)(s0 + tid) * 32 + h];
#pragma unroll
    for (int off = 1; off < 64; off <<= 1) {
      float t = __shfl_up(gv, off, 64);
      if (tid >= off) gv += t;
    }
    sGc[tid] = gv;
  }
  __syncthreads();

  const bf16_t* qrow = qb + (size_t)s0 * 2048 + kh * 128;
  const bf16_t* krow = kb + (size_t)s0 * 2048 + kh * 128;
  bf16x8 aq[4];
#pragma unroll
  for (int ks = 0; ks < 4; ks++)
    aq[ks] = *(const bf16x8*)(qrow + (size_t)m * 2048 + ks * 32 + quad * 8);
  f32x4 accA[4];
#pragma unroll
  for (int nt = 0; nt < 4; nt++) { f32x4 z = {0.f, 0.f, 0.f, 0.f}; accA[nt] = z; }
#pragma unroll
  for (int nt = 0; nt < 4; nt++)
#pragma unroll
    for (int ks = 0; ks < 4; ks++) {
      bf16x8 bk = *(const bf16x8*)(krow + (size_t)(nt * 16 + l15) * 2048 + ks * 32 + quad * 8);
      accA[nt] = MFMA_BF16(aq[ks], bk, accA[nt]);
    }
#pragma unroll
  for (int nt = 0; nt < 4; nt++) {
    int j = nt * 16 + l15;
#pragma unroll
    for (int r = 0; r < 4; r++) {
      int i = w * 16 + quad * 4 + r;
      float a = (i >= j) ? accA[nt][r] * __expf(sGc[i] - sGc[j]) : 0.f;
      sAp[i * 68 + j] = packhl(a);
    }
  }
  __syncthreads();

  FragPair Aa[2];
#pragma unroll
  for (int ks = 0; ks < 2; ks++) {
    unsigned u[8];
    load8u(u, sAp + m * 68 + ks * 32 + quad * 8);
    Aa[ks] = unpack8(u);
  }
  f32x4 accO[8];
#pragma unroll
  for (int nt = 0; nt < 8; nt++) {
    size_t base = ((size_t)h * 4096 + s0 + w * 16 + quad * 4) * 128 + nt * 16 + l15;
    f32x4 z;
    z[0] = bf2f(outp[base]); z[1] = bf2f(outp[base + 128]);
    z[2] = bf2f(outp[base + 256]); z[3] = bf2f(outp[base + 384]);
    accO[nt] = z;
  }
#pragma unroll
  for (int nt = 0; nt < 8; nt++)
#pragma unroll
    for (int ks = 0; ks < 2; ks++) {
      bf16x8 bv = *(const bf16x8*)(vnT + ((size_t)(h * 64 + ci) * 128 + nt * 16 + l15) * 64 +
                                   ks * 32 + quad * 8);
      accO[nt] = MFMA_BF16(Aa[ks].hi, bv, accO[nt]);
      accO[nt] = MFMA_BF16(Aa[ks].lo, bv, accO[nt]);
    }

  // gated RMSNorm: xf = core*silu(z); xf *= rsqrt(mean(xf^2)+eps)*norm_w
  float xv[8][4];
  float ss[4] = {0.f, 0.f, 0.f, 0.f};
#pragma unroll
  for (int nt = 0; nt < 8; nt++) {
    int dv = nt * 16 + l15;
#pragma unroll
    for (int r = 0; r < 4; r++) {
      int s = s0 + w * 16 + quad * 4 + r;
      float z = bf2f(zb[(size_t)s * 4096 + h * 128 + dv]);
      float gate = z / (1.f + __expf(-z));
      float val = accO[nt][r] * gate;
      xv[nt][r] = val;
      ss[r] += val * val;
    }
  }
#pragma unroll
  for (int off = 1; off < 16; off <<= 1) {
#pragma unroll
    for (int r = 0; r < 4; r++) ss[r] += __shfl_xor(ss[r], off, 64);
  }
  float rs[4];
#pragma unroll
  for (int r = 0; r < 4; r++) rs[r] = rsqrtf(ss[r] * (1.f / 128.f) + 1e-6f);
#pragma unroll
  for (int nt = 0; nt < 8; nt++) {
    int dv = nt * 16 + l15;
    float nwv = nw[dv];
#pragma unroll
    for (int r = 0; r < 4; r++) {
      int s = s0 + w * 16 + quad * 4 + r;
      xf[(size_t)s * 4096 + h * 128 + dv] = f2bf(xv[nt][r] * rs[r] * nwv);
    }
  }
}

// ---------------------------------------------------------------------------
extern "C" void kernel_launch(void* const* d_in, const int* in_sizes, int n_in,
                              void* d_out, int out_size, void* d_ws, size_t ws_size,
                              hipStream_t stream) {
  const float* hs = (const float*)d_in[0];
  const float* Wqkvz = (const float*)d_in[1];
  const float* Wba = (const float*)d_in[2];
  const float* convk = (const float*)d_in[3];
  const float* A_log = (const float*)d_in[4];
  const float* dtb = (const float*)d_in[5];
  const float* nw = (const float*)d_in[6];
  const float* Wout = (const float*)d_in[7];
  float* out = (float*)d_out;
  char* ws = (char*)d_ws;

  // Arena: 252,706,816 B with static aliasing.
  const size_t NEED = 252706816u;
  if (ws_size < NEED) return;  // diagnostic: absmax==max|ref| => ws too small

  bf16_t* hsbf = (bf16_t*)(ws + 0);              // 16.78 MB [t1-t2]
  bf16_t* wqkT = (bf16_t*)(ws + 16777216);       // 50.33 MB [t1-t2]
  bf16_t* qb   = (bf16_t*)(ws + 0);              // 16.78 MB [t4-t7] (over hsbf)
  bf16_t* kb   = (bf16_t*)(ws + 16777216);       // 16.78 MB [t4-t7] (over wqkT)
  bf16_t* vb   = (bf16_t*)(ws + 33554432);       // 33.55 MB [t4-t5] (over wqkT)
  bf16_t* vnT  = (bf16_t*)(ws + 33554432);       // 33.55 MB [t6-t7] (over vb)
  bf16_t* qkvb = (bf16_t*)(ws + 67108864);       // 67.11 MB [t2-t4]
  float*  vi   = (float*)(ws + 67108864);        // 67.11 MB [t5-t6] (over qkvb)
  bf16_t* xf   = (bf16_t*)(ws + 67108864);       // 33.55 MB [t7-t9] (over vi)
  bf16_t* zb   = (bf16_t*)(ws + 134217728);      // 33.55 MB [t2-t7]
  float*  gbuf = (float*)(ws + 167772160);       // 0.52 MB
  float*  bbuf = (float*)(ws + 168296448);       // 0.52 MB
  bf16_t* kcdn = (bf16_t*)(ws + 168820736);      // 33.55 MB [t5-t6]
  bf16_t* woutT= (bf16_t*)(ws + 168820736);      // 16.78 MB [t8-t9] (over kcdn)
  bf16_t* outp = (bf16_t*)(ws + 202375168);      // 33.55 MB [t6-t7]
  bf16_t* kbT  = (bf16_t*)(ws + 235929600);      // 16.78 MB [t4.5-t6] -> ends 252,706,816

  k_cvt<<<8192, 256, 0, stream>>>(hs, hsbf, 4096 * 2048);                      // t1
  k_transpose_cvt<<<dim3(192, 32), 256, 0, stream>>>(Wqkvz, wqkT, 2048, 12288);
  k_gemm_qkvz<<<dim3(48, 16), 512, 0, stream>>>(hsbf, wqkT, qkvb, zb,          // t2
                                                4096, 12288, 2048);
  k_ba<<<128, 256, 0, stream>>>(hs, Wba, A_log, dtb, gbuf, bbuf);              // t3
  k_conv<<<dim3(32, 32), 256, 0, stream>>>(qkvb, convk, qb, kb, vb);           // t4
  k_ktrans<<<1024, 256, 0, stream>>>(kb, kbT);                                 // t4.5
  k_phaseA<<<2048, 256, 0, stream>>>(kb, vb, gbuf, bbuf, vi, kcdn);            // t5
  k_phaseB<<<256, 256, 0, stream>>>(qb, kbT, gbuf, vi, kcdn, vnT, outp);       // t6
  k_phaseC<<<2048, 256, 0, stream>>>(qb, kb, gbuf, vnT, outp, zb, nw, xf);     // t7
  k_transpose_cvt<<<dim3(32, 64), 256, 0, stream>>>(Wout, woutT, 4096, 2048);  // t8
  k_gemm<<<dim3(16, 32), 256, 0, stream>>>(xf, woutT, out, 4096, 2048, 4096);  // t9
}

// Round 8
// 1017.565 us; speedup vs baseline: 1.2431x; 1.0036x over previous
//
#include <hip/hip_runtime.h>

// ---------------------------------------------------------------------------
// Qwen3Next GatedDeltaNet forward, MI355X/gfx950. v11:
//  - k_gemm_qkvz = v9 8-phase with COMPILER-COUNTED lgkm waits: reads issued
//    pre-barrier (v9 order, B before A), NO wholesale lgkmcnt(0) after the
//    barrier, no lgkm8 throttle. hipcc emits lgkmcnt(N) chains before each
//    dependent MFMA (m97-documented), so first MFMA starts when its operands
//    land and the remaining read service hides under the MFMA cluster.
//    vmcnt(4)@Ph4/Ph8 publish logic unchanged (asm "memory" fences reads).
//  - XCD column map kept (FETCH 410->148 MB verified in v6).
// ---------------------------------------------------------------------------

typedef __attribute__((ext_vector_type(8))) __bf16 bf16x8;
typedef __attribute__((ext_vector_type(4))) float f32x4;
typedef __bf16 bf16_t;

#define MFMA_BF16(A, B, C) __builtin_amdgcn_mfma_f32_16x16x32_bf16((A), (B), (C), 0, 0, 0)

__device__ __forceinline__ void async16(const bf16_t* g, bf16_t* l) {
  __builtin_amdgcn_global_load_lds(
      (const __attribute__((address_space(1))) unsigned*)g,
      (__attribute__((address_space(3))) unsigned*)l, 16, 0, 0);
}

__device__ __forceinline__ bf16_t f2bf(float x) {
  unsigned u = __builtin_bit_cast(unsigned, x);
  unsigned r = u + 0x7fffu + ((u >> 16) & 1u);
  unsigned short s = (unsigned short)(r >> 16);
  return __builtin_bit_cast(bf16_t, s);
}
__device__ __forceinline__ float bf2f(bf16_t b) {
  unsigned short s = __builtin_bit_cast(unsigned short, b);
  unsigned u = ((unsigned)s) << 16;
  return __builtin_bit_cast(float, u);
}
__device__ __forceinline__ unsigned packhl(float x) {
  bf16_t h = f2bf(x);
  bf16_t l = f2bf(x - bf2f(h));
  return (((unsigned)__builtin_bit_cast(unsigned short, h)) << 16) |
         (unsigned)__builtin_bit_cast(unsigned short, l);
}
__device__ __forceinline__ float upk(unsigned u) {
  return __builtin_bit_cast(float, u & 0xffff0000u) +
         __builtin_bit_cast(float, u << 16);
}

struct FragPair { bf16x8 hi, lo; };

__device__ __forceinline__ void load8(float v[8], const float* p) {
  float4 a = *(const float4*)p;
  float4 b = *(const float4*)(p + 4);
  v[0] = a.x; v[1] = a.y; v[2] = a.z; v[3] = a.w;
  v[4] = b.x; v[5] = b.y; v[6] = b.z; v[7] = b.w;
}
__device__ __forceinline__ void load8u(unsigned v[8], const unsigned* p) {
  uint4 a = *(const uint4*)p;
  uint4 b = *(const uint4*)(p + 4);
  v[0] = a.x; v[1] = a.y; v[2] = a.z; v[3] = a.w;
  v[4] = b.x; v[5] = b.y; v[6] = b.z; v[7] = b.w;
}
__device__ __forceinline__ FragPair split8(const float v[8]) {
  FragPair f;
#pragma unroll
  for (int j = 0; j < 8; j++) {
    bf16_t h = f2bf(v[j]);
    f.hi[j] = h;
    f.lo[j] = f2bf(v[j] - bf2f(h));
  }
  return f;
}
__device__ __forceinline__ FragPair unpack8(const unsigned v[8]) {
  FragPair f;
#pragma unroll
  for (int j = 0; j < 8; j++) {
    f.hi[j] = __builtin_bit_cast(bf16_t, (unsigned short)(v[j] >> 16));
    f.lo[j] = __builtin_bit_cast(bf16_t, (unsigned short)(v[j] & 0xffffu));
  }
  return f;
}

// ---------------------------------------------------------------------------
// elementwise f32 -> bf16
__global__ void k_cvt(const float* __restrict__ in, bf16_t* __restrict__ out, int n) {
  int i = (blockIdx.x * 256 + threadIdx.x) * 4;
  if (i + 3 < n) {
    float4 v = *(const float4*)(in + i);
    out[i + 0] = f2bf(v.x); out[i + 1] = f2bf(v.y);
    out[i + 2] = f2bf(v.z); out[i + 3] = f2bf(v.w);
  }
}

// transpose [K][N] f32 -> [N][K] bf16
__global__ void k_transpose_cvt(const float* __restrict__ in, bf16_t* __restrict__ out,
                                int K, int N) {
  __shared__ bf16_t tile[64 * 65];
  int n0 = blockIdx.x * 64, k0 = blockIdx.y * 64;
  int c = threadIdx.x & 63, rg = threadIdx.x >> 6;
#pragma unroll
  for (int rr = 0; rr < 16; rr++) {
    int r = rr * 4 + rg;
    tile[c * 65 + r] = f2bf(in[(size_t)(k0 + r) * N + n0 + c]);
  }
  __syncthreads();
#pragma unroll
  for (int rr = 0; rr < 16; rr++) {
    int r = rr * 4 + rg;
    out[(size_t)(n0 + r) * K + k0 + c] = tile[r * 65 + c];
  }
}

// ---------------------------------------------------------------------------
// per-chunk k transpose: kb[s][2048] -> kbT[kh*64+ci][dk=128][s=64] bf16
__global__ void k_ktrans(const bf16_t* __restrict__ kb, bf16_t* __restrict__ kbT) {
  __shared__ __align__(16) bf16_t t[128][72];
  int kh = blockIdx.x >> 6, ci = blockIdx.x & 63, s0 = ci * 64;
  int s = threadIdx.x & 63, dg = threadIdx.x >> 6;
  const bf16_t* src = kb + (size_t)(s0 + s) * 2048 + kh * 128 + dg * 32;
#pragma unroll
  for (int j = 0; j < 4; j++) {
    bf16x8 v = *(const bf16x8*)(src + j * 8);
#pragma unroll
    for (int e = 0; e < 8; e++) t[dg * 32 + j * 8 + e][s] = v[e];
  }
  __syncthreads();
  int d = threadIdx.x >> 1, sh = (threadIdx.x & 1) * 32;
  bf16_t* dst = kbT + ((size_t)blockIdx.x * 128 + d) * 64 + sh;
#pragma unroll
  for (int j = 0; j < 4; j++)
    *(bf16x8*)(dst + j * 8) = *(const bf16x8*)(&t[d][sh + j * 8]);
}

// ---------------------------------------------------------------------------
// Old-structure swizzled GEMM (kept for t9: C[M,N]=A*BT^T fp32 out, 128^2 tile)
__global__ __launch_bounds__(256) void k_gemm(const bf16_t* __restrict__ A,
                                              const bf16_t* __restrict__ BT,
                                              float* __restrict__ C, int M, int N, int K) {
  __shared__ __align__(16) bf16_t sA[128 * 32];
  __shared__ __align__(16) bf16_t sB[128 * 32];
  const int tid = threadIdx.x;
  const int lane = tid & 63, w = tid >> 6;
  const int quad = lane >> 4, l15 = lane & 15;
  const int m0 = blockIdx.y * 128, n0 = blockIdx.x * 128;
  const int wm = (w >> 1) * 64, wn = (w & 1) * 64;
  f32x4 acc[4][4];
#pragma unroll
  for (int a = 0; a < 4; a++)
#pragma unroll
    for (int b = 0; b < 4; b++) { f32x4 z = {0.f, 0.f, 0.f, 0.f}; acc[a][b] = z; }
  const int sb = (lane & 7) ^ ((lane >> 3) & 7);
  const int srow = ((tid >> 3) << 1) + (sb >> 2);   // 0..63
  const int scol = (sb & 3) * 8;
  const bf16_t* gA = A + (size_t)(m0 + srow) * K + scol;
  const bf16_t* gB = BT + (size_t)(n0 + srow) * K + scol;
  bf16_t* lA = sA + w * 512;   // wave-uniform base; HW adds lane*16B
  bf16_t* lB = sB + w * 512;
  const int rh = l15 >> 1;
  const int bs = (((l15 & 1) << 2) + quad) ^ rh;
  const int foff = rh * 64 + bs * 8;
  for (int kt = 0; kt < K; kt += 32) {
    async16(gA + kt, lA);
    async16(gA + (size_t)64 * K + kt, lA + 2048);
    async16(gB + kt, lB);
    async16(gB + (size_t)64 * K + kt, lB + 2048);
    __syncthreads();
    bf16x8 af[4], bfv[4];
#pragma unroll
    for (int t = 0; t < 4; t++) {
      af[t]  = *(const bf16x8*)(sA + ((wm >> 1) + t * 8) * 64 + foff);
      bfv[t] = *(const bf16x8*)(sB + ((wn >> 1) + t * 8) * 64 + foff);
    }
#pragma unroll
    for (int mt = 0; mt < 4; mt++)
#pragma unroll
      for (int nt = 0; nt < 4; nt++)
        acc[mt][nt] = MFMA_BF16(af[mt], bfv[nt], acc[mt][nt]);
    __syncthreads();
  }
#pragma unroll
  for (int mt = 0; mt < 4; mt++)
#pragma unroll
    for (int nt = 0; nt < 4; nt++) {
      int row0 = m0 + wm + mt * 16 + quad * 4;
      int col = n0 + wn + nt * 16 + l15;
#pragma unroll
      for (int r = 0; r < 4; r++)
        C[(size_t)(row0 + r) * N + col] = acc[mt][nt][r];
    }
}

// ---------------------------------------------------------------------------
// GEMM1: 8-phase, reads pre-barrier + compiler-counted lgkm waits. 256x256
// tile, BK=64, 512 thr / 8 waves (2Mx4N), per-wave 128x64. LDS: 2 buffers x
// {A0,A1,B0,B1} half-tiles (16KB each) = 128 KiB.
//
// Per 2 K-tiles, 8 phases:
//  Ph1 rd B(n0-1)+A(m0-3)[12] | stg b1A0 | bar | MFMA (compiler lgkm) | bar
//  Ph2 rd B(n2-3)[4]          | stg b1A1 | bar | MFMA | bar
//  Ph3 rd A(m4-7)[8]          | stg b0B0'| bar | MFMA | bar
//  Ph4 [0]                    | stg b0B1'| vmcnt4 | bar | MFMA | bar
//  Ph5-8: same on buf1, staging b0A0'/b0A1'/b1B0'/b1B1', vmcnt4 @Ph8.
// No wholesale lgkmcnt(0): hipcc emits counted lgkm before each dependent
// MFMA, so read service overlaps the MFMA cluster. vmcnt(4) retires the
// buffer read next phase; 2 newest half-tiles stay in flight; drain 0 at tail.
__global__ __launch_bounds__(512, 2) void k_gemm_qkvz(const bf16_t* __restrict__ A,
                                                      const bf16_t* __restrict__ BT,
                                                      bf16_t* __restrict__ qkvb,
                                                      bf16_t* __restrict__ zb,
                                                      int M, int N, int K) {
  __shared__ __align__(16) bf16_t sL[2 * 4 * 8192];   // 128 KiB
  const int tid = threadIdx.x;
  const int lane = tid & 63, w = tid >> 6;
  const int quad = lane >> 4, l15 = lane & 15;

  // XCD column map (v6, verified): XCD x owns bx in [6x,6x+6), all by.
  int id = blockIdx.y * gridDim.x + blockIdx.x;
  const int xcd = id & 7, jj = id >> 3;
  const int bx = xcd * 6 + (jj % 6), by = jj / 6;
  const int m0 = by * 256, n0 = bx * 256;
  const int wm = (w >> 2) * 128, wn = (w & 3) * 64;
  const int hA = (w >> 2);             // 0/1: A half this wave reads
  const int hB = 2 + ((w & 3) >> 1);   // 2/3: B half this wave reads
  const int brow0 = wn & 64;           // row base within B half

  f32x4 acc[8][4];
#pragma unroll
  for (int m = 0; m < 8; m++)
#pragma unroll
    for (int n = 0; n < 4; n++) { f32x4 z = {0.f, 0.f, 0.f, 0.f}; acc[m][n] = z; }

  // staging source geometry (verified): per lane row rbase(+64), phys block
  // lane&7 holding logical block (lane&7)^(row&7)  (row&7 == (lane>>3)&7).
  const int rbase = w * 8 + (lane >> 3);
  const int sq = (lane & 7) ^ ((lane >> 3) & 7);
  const bf16_t* gb[4];
  gb[0] = A + (size_t)(m0 + rbase) * K + sq * 8;
  gb[1] = A + (size_t)(m0 + 128 + rbase) * K + sq * 8;
  gb[2] = BT + (size_t)(n0 + rbase) * K + sq * 8;
  gb[3] = BT + (size_t)(n0 + 128 + rbase) * K + sq * 8;
  const size_t j64 = (size_t)64 * K;

  bf16x8 afr[4][2], bf01[2][2], bf23[2][2];
  const int NI = K >> 7;   // iterations of 2 K-tiles (16 for K=2048)

  auto stg = [&](int cb, int h, int kt) {
    const bf16_t* s = gb[h] + (size_t)kt * 64;
    bf16_t* d = sL + (cb * 4 + h) * 8192 + w * 512;
    async16(s, d);
    async16(s + j64, d + 4096);
  };
  auto ldA = [&](int cb, int mg) {
    const bf16_t* base = sL + (cb * 4 + hA) * 8192;
#pragma unroll
    for (int m = 0; m < 4; m++)
#pragma unroll
      for (int ks = 0; ks < 2; ks++)
        afr[m][ks] = *(const bf16x8*)(base + (mg * 64 + m * 16 + l15) * 64 +
                                      (((ks * 4 + quad) ^ (l15 & 7)) * 8));
  };
  auto ldB = [&](int cb, int ng, bf16x8 (&bf)[2][2]) {
    const bf16_t* base = sL + (cb * 4 + hB) * 8192;
#pragma unroll
    for (int n = 0; n < 2; n++)
#pragma unroll
      for (int ks = 0; ks < 2; ks++)
        bf[n][ks] = *(const bf16x8*)(base + (brow0 + ng * 32 + n * 16 + l15) * 64 +
                                     (((ks * 4 + quad) ^ (l15 & 7)) * 8));
  };
  auto mm = [&](int mg, int ng, bf16x8 (&bf)[2][2]) {
    __builtin_amdgcn_s_setprio(1);
#pragma unroll
    for (int m = 0; m < 4; m++)
#pragma unroll
      for (int n = 0; n < 2; n++)
#pragma unroll
        for (int ks = 0; ks < 2; ks++)
          acc[mg * 4 + m][ng * 2 + n] =
              MFMA_BF16(afr[m][ks], bf[n][ks], acc[mg * 4 + m][ng * 2 + n]);
    __builtin_amdgcn_s_setprio(0);
  };

  // prologue: kt0 all halves, kt1 B halves (kt1 A halves come at Ph1/Ph2 of i=0)
#pragma unroll
  for (int h = 0; h < 4; h++) stg(0, h, 0);
  stg(1, 2, 1);
  stg(1, 3, 1);
  asm volatile("s_waitcnt vmcnt(4)" ::: "memory");   // kt0 complete
  __builtin_amdgcn_s_barrier();

  for (int i = 0; i < NI; ++i) {
    const int k2 = 2 * i;
    const bool more = (i + 1 < NI);
    // ---------- buf0 : K-tile k2 ----------
    // Ph1: reads issued pre-barrier (B first: arrival matches consumption)
    ldB(0, 0, bf01); ldA(0, 0);
    stg(1, 0, k2 + 1);
    __builtin_amdgcn_s_barrier();
    mm(0, 0, bf01);
    __builtin_amdgcn_s_barrier();
    // Ph2
    ldB(0, 1, bf23);
    stg(1, 1, k2 + 1);
    __builtin_amdgcn_s_barrier();
    mm(0, 1, bf23);
    __builtin_amdgcn_s_barrier();
    // Ph3
    ldA(0, 1);
    if (more) stg(0, 2, k2 + 2);
    __builtin_amdgcn_s_barrier();
    mm(1, 0, bf01);
    __builtin_amdgcn_s_barrier();
    // Ph4
    if (more) {
      stg(0, 3, k2 + 2);
      asm volatile("s_waitcnt vmcnt(4)" ::: "memory");
    } else {
      asm volatile("s_waitcnt vmcnt(0)" ::: "memory");
    }
    __builtin_amdgcn_s_barrier();
    mm(1, 1, bf23);
    __builtin_amdgcn_s_barrier();
    // ---------- buf1 : K-tile k2+1 ----------
    // Ph5
    ldB(1, 0, bf01); ldA(1, 0);
    if (more) stg(0, 0, k2 + 2);
    __builtin_amdgcn_s_barrier();
    mm(0, 0, bf01);
    __builtin_amdgcn_s_barrier();
    // Ph6
    ldB(1, 1, bf23);
    if (more) stg(0, 1, k2 + 2);
    __builtin_amdgcn_s_barrier();
    mm(0, 1, bf23);
    __builtin_amdgcn_s_barrier();
    // Ph7
    ldA(1, 1);
    if (more) stg(1, 2, k2 + 3);
    __builtin_amdgcn_s_barrier();
    mm(1, 0, bf01);
    __builtin_amdgcn_s_barrier();
    // Ph8
    if (more) {
      stg(1, 3, k2 + 3);
      asm volatile("s_waitcnt vmcnt(4)" ::: "memory");
    } else {
      asm volatile("s_waitcnt vmcnt(0)" ::: "memory");
    }
    __builtin_amdgcn_s_barrier();
    mm(1, 1, bf23);
    __builtin_amdgcn_s_barrier();
  }

  // epilogue: split columns into qkv (kh*512+rr) and z (kh*256+rr-512)
#pragma unroll
  for (int n = 0; n < 4; n++) {
    int c = n0 + wn + n * 16 + l15;        // 0..12287
    int kh = c / 768;
    int rr = c - kh * 768;
    bool isz = (rr >= 512);
    bf16_t* dst = isz ? zb : qkvb;
    size_t stride = isz ? 4096 : 8192;
    size_t coff = isz ? (size_t)(kh * 256 + (rr - 512)) : (size_t)(kh * 512 + rr);
#pragma unroll
    for (int m = 0; m < 8; m++) {
      int row0 = m0 + wm + m * 16 + quad * 4;
#pragma unroll
      for (int r = 0; r < 4; r++)
        dst[(size_t)(row0 + r) * stride + coff] = f2bf(acc[m][n][r]);
    }
  }
}

// ---------------------------------------------------------------------------
// ba = hs @ W_ba  ->  beta = sigmoid(b), g = -exp(A_log)*softplus(a+dt_bias)
__global__ __launch_bounds__(256) void k_ba(const float* __restrict__ hs,
                                            const float* __restrict__ Wba,
                                            const float* __restrict__ A_log,
                                            const float* __restrict__ dtb,
                                            float* __restrict__ g, float* __restrict__ beta) {
  __shared__ float sH[4][2048];
  int s0 = blockIdx.x * 32;
  int c = threadIdx.x & 63, sg = threadIdx.x >> 6;
  for (int rg = 0; rg < 8; rg++) {
    __syncthreads();
    for (int i = threadIdx.x; i < 2048; i += 256) {  // float4 units
      int r = i >> 9, kk = (i & 511) * 4;
      *(float4*)(&sH[r][kk]) = *(const float4*)(hs + (size_t)(s0 + rg * 4 + r) * 2048 + kk);
    }
    __syncthreads();
    float dot = 0.f;
    for (int kk = 0; kk < 2048; kk += 4) {
      float4 hv = *(const float4*)(&sH[sg][kk]);
      dot += hv.x * Wba[(kk + 0) * 64 + c] + hv.y * Wba[(kk + 1) * 64 + c] +
             hv.z * Wba[(kk + 2) * 64 + c] + hv.w * Wba[(kk + 3) * 64 + c];
    }
    int s = s0 + rg * 4 + sg;
    int hh = c >> 2, j = c & 3;
    if (j < 2) {
      int vh = hh * 2 + j;
      beta[s * 32 + vh] = 1.f / (1.f + __expf(-dot));
    } else {
      int vh = hh * 2 + (j - 2);
      float x = dot + dtb[vh];
      float sp = (x > 20.f) ? x : log1pf(__expf(x));
      g[s * 32 + vh] = -__expf(A_log[vh]) * sp;
    }
  }
}

// ---------------------------------------------------------------------------
// depthwise causal conv (KSZ=4) + silu; bf16 in (qkvb layout kh*512+r), bf16 out
__global__ void k_conv(const bf16_t* __restrict__ qkvb, const float* __restrict__ ck,
                       bf16_t* __restrict__ qb, bf16_t* __restrict__ kb,
                       bf16_t* __restrict__ vb) {
  int c = blockIdx.x * 256 + threadIdx.x;   // 0..8191 global conv channel
  int s0 = blockIdx.y * 128;
  int col, dstc, dstride;
  bf16_t* dst;
  float scale = 1.0f;
  if (c < 2048) {
    int hh = c >> 7, d = c & 127;
    col = hh * 512 + d; dst = qb; dstc = c; dstride = 2048;
    scale = 0.08838834764831845f;  // rsqrt(DK)
  } else if (c < 4096) {
    int cc = c - 2048, hh = cc >> 7, d = cc & 127;
    col = hh * 512 + 128 + d; dst = kb; dstc = cc; dstride = 2048;
  } else {
    int cc = c - 4096, vh = cc >> 7, d = cc & 127;
    col = (vh >> 1) * 512 + 256 + (vh & 1) * 128 + d; dst = vb; dstc = cc; dstride = 4096;
  }
  float w0 = ck[c], w1 = ck[8192 + c], w2 = ck[2 * 8192 + c], w3 = ck[3 * 8192 + c];
  float x0 = 0.f, x1 = 0.f, x2 = 0.f;
  if (s0 >= 3) {
    x0 = bf2f(qkvb[(size_t)(s0 - 3) * 8192 + col]);
    x1 = bf2f(qkvb[(size_t)(s0 - 2) * 8192 + col]);
    x2 = bf2f(qkvb[(size_t)(s0 - 1) * 8192 + col]);
  }
  for (int s = s0; s < s0 + 128; s++) {
    float x3 = bf2f(qkvb[(size_t)s * 8192 + col]);
    float y = w0 * x0 + w1 * x1 + w2 * x2 + w3 * x3;
    y = y / (1.f + __expf(-y));
    dst[(size_t)s * dstride + dstc] = f2bf(y * scale);
    x0 = x1; x1 = x2; x2 = x3;
  }
}

// ---------------------------------------------------------------------------
// phase A: per (head, chunk): L, attn=(I-L)^-1 via nilpotent squaring,
// vi = attn@(beta v) (f32), kcdn = -attn@(beta e^gc k) (bf16)
__global__ __launch_bounds__(256) void k_phaseA(const bf16_t* __restrict__ kb,
                                                const bf16_t* __restrict__ vb,
                                                const float* __restrict__ g,
                                                const float* __restrict__ beta,
                                                float* __restrict__ vi,
                                                bf16_t* __restrict__ kcdn) {
  __shared__ __align__(16) char smem[36608];
  float* sGc = (float*)smem;               // [64]
  float* sBt = (float*)(smem + 256);       // [64]
  float* sBE = (float*)(smem + 512);       // [64]
  float* sP  = (float*)(smem + 768);       // [64][68] f32 -> ends 18176
  bf16_t* sQ  = (bf16_t*)(smem + 18176);   // [64][72] -> ends 27392
  bf16_t* sQT = (bf16_t*)(smem + 27392);   // [64][72] -> ends 36608
  bf16_t* sVT = (bf16_t*)(smem + 18176);   // overlay (after squaring)
  bf16_t* sKT = (bf16_t*)(smem + 27392);   // overlay

  const int tid = threadIdx.x, lane = tid & 63, w = tid >> 6;
  const int quad = lane >> 4, l15 = lane & 15;
  const int h = blockIdx.x >> 6, ci = blockIdx.x & 63;
  const int kh = h >> 1, s0 = ci * 64;
  const int m = w * 16 + l15;

  if (tid < 64) {
    float gv = g[(size_t)(s0 + tid) * 32 + h];
    float bv = beta[(size_t)(s0 + tid) * 32 + h];
#pragma unroll
    for (int off = 1; off < 64; off <<= 1) {
      float t = __shfl_up(gv, off, 64);
      if (tid >= off) gv += t;
    }
    sGc[tid] = gv; sBt[tid] = bv; sBE[tid] = bv * __expf(gv);
  }
  __syncthreads();

  // ---- raw K@K^T (exact bf16 inputs) ----
  const bf16_t* krow = kb + (size_t)s0 * 2048 + kh * 128;
  bf16x8 ak[4];
#pragma unroll
  for (int ks = 0; ks < 4; ks++)
    ak[ks] = *(const bf16x8*)(krow + (size_t)m * 2048 + ks * 32 + quad * 8);
  f32x4 accL[4];
#pragma unroll
  for (int nt = 0; nt < 4; nt++) { f32x4 z = {0.f, 0.f, 0.f, 0.f}; accL[nt] = z; }
#pragma unroll
  for (int nt = 0; nt < 4; nt++)
#pragma unroll
    for (int ks = 0; ks < 4; ks++) {
      bf16x8 bk = *(const bf16x8*)(krow + (size_t)(nt * 16 + l15) * 2048 + ks * 32 + quad * 8);
      accL[nt] = MFMA_BF16(ak[ks], bk, accL[nt]);
    }
#pragma unroll
  for (int nt = 0; nt < 4; nt++) {
    int j = nt * 16 + l15;
#pragma unroll
    for (int r = 0; r < 4; r++) {
      int i = w * 16 + quad * 4 + r;
      float Lij = (i > j) ? (-accL[nt][r] * sBt[i] * __expf(sGc[i] - sGc[j])) : 0.f;
      sP[i * 68 + j] = ((i == j) ? 1.f : 0.f) + Lij;
      bf16_t q16 = f2bf(Lij);
      sQ[i * 72 + j] = q16;
      sQT[j * 72 + i] = q16;
    }
  }
  __syncthreads();

  // ---- attn = (I+L)(I+L^2)...(I+L^32); P holds running product ----
  for (int it = 0; it < 5; it++) {
    f32x4 accQ[4];
#pragma unroll
    for (int nt = 0; nt < 4; nt++) { f32x4 z = {0.f, 0.f, 0.f, 0.f}; accQ[nt] = z; }
    bf16x8 qa[2];
#pragma unroll
    for (int ks = 0; ks < 2; ks++)
      qa[ks] = *(const bf16x8*)(sQ + m * 72 + ks * 32 + quad * 8);
#pragma unroll
    for (int nt = 0; nt < 4; nt++)
#pragma unroll
      for (int ks = 0; ks < 2; ks++) {
        bf16x8 qv = *(const bf16x8*)(sQT + (nt * 16 + l15) * 72 + ks * 32 + quad * 8);
        accQ[nt] = MFMA_BF16(qa[ks], qv, accQ[nt]);
      }
    __syncthreads();
#pragma unroll
    for (int nt = 0; nt < 4; nt++) {
      int j = nt * 16 + l15;
#pragma unroll
      for (int r = 0; r < 4; r++) {
        int i = w * 16 + quad * 4 + r;
        bf16_t q16 = f2bf(accQ[nt][r]);
        sQ[i * 72 + j] = q16;
        sQT[j * 72 + i] = q16;
      }
    }
    __syncthreads();
    // P += P @ Q (wave owns its 16 rows -> in-place safe)
    f32x4 accP[4];
#pragma unroll
    for (int nt = 0; nt < 4; nt++) { f32x4 z = {0.f, 0.f, 0.f, 0.f}; accP[nt] = z; }
    FragPair pa[2];
#pragma unroll
    for (int ks = 0; ks < 2; ks++) {
      float v[8];
      load8(v, sP + m * 68 + ks * 32 + quad * 8);
      pa[ks] = split8(v);
    }
#pragma unroll
    for (int nt = 0; nt < 4; nt++)
#pragma unroll
      for (int ks = 0; ks < 2; ks++) {
        bf16x8 qv = *(const bf16x8*)(sQT + (nt * 16 + l15) * 72 + ks * 32 + quad * 8);
        accP[nt] = MFMA_BF16(pa[ks].hi, qv, accP[nt]);
        accP[nt] = MFMA_BF16(pa[ks].lo, qv, accP[nt]);
      }
#pragma unroll
    for (int nt = 0; nt < 4; nt++) {
      int j = nt * 16 + l15;
#pragma unroll
      for (int r = 0; r < 4; r++) {
        int i = w * 16 + quad * 4 + r;
        sP[i * 68 + j] += accP[nt][r];
      }
    }
  }

  // ---- A-operand splits: attn*beta (for vi) and attn*beta*e^gc (for kcd) ----
  FragPair paV[2], paK[2];
#pragma unroll
  for (int ks = 0; ks < 2; ks++) {
    float v[8];
    load8(v, sP + m * 68 + ks * 32 + quad * 8);
    float vv[8], vk[8];
#pragma unroll
    for (int jj = 0; jj < 8; jj++) {
      int i = ks * 32 + quad * 8 + jj;
      vv[jj] = v[jj] * sBt[i];
      vk[jj] = v[jj] * sBE[i];
    }
    paV[ks] = split8(vv);
    paK[ks] = split8(vk);
  }

  // ---- vi / kcdn in two dv halves (sVT/sKT overlay sQ/sQT) ----
  for (int hf = 0; hf < 2; hf++) {
    __syncthreads();  // prior sQT/sVT/sKT readers done before overwrite
    {
      int sidx = tid & 63, dg = tid >> 6;
      const bf16_t* vsrc = vb + (size_t)(s0 + sidx) * 4096 + h * 128 + hf * 64 + dg * 16;
      const bf16_t* ksrc = kb + (size_t)(s0 + sidx) * 2048 + kh * 128 + hf * 64 + dg * 16;
      bf16x8 v0 = *(const bf16x8*)vsrc;
      bf16x8 v1 = *(const bf16x8*)(vsrc + 8);
      bf16x8 k0 = *(const bf16x8*)ksrc;
      bf16x8 k1 = *(const bf16x8*)(ksrc + 8);
#pragma unroll
      for (int e = 0; e < 8; e++) {
        sVT[(dg * 16 + e) * 72 + sidx] = v0[e];
        sVT[(dg * 16 + 8 + e) * 72 + sidx] = v1[e];
        sKT[(dg * 16 + e) * 72 + sidx] = k0[e];
        sKT[(dg * 16 + 8 + e) * 72 + sidx] = k1[e];
      }
    }
    __syncthreads();
    f32x4 accV[4], accK[4];
#pragma unroll
    for (int nt = 0; nt < 4; nt++) {
      f32x4 z = {0.f, 0.f, 0.f, 0.f};
      accV[nt] = z; accK[nt] = z;
    }
#pragma unroll
    for (int nt = 0; nt < 4; nt++)
#pragma unroll
      for (int ks = 0; ks < 2; ks++) {
        bf16x8 bv = *(const bf16x8*)(sVT + (nt * 16 + l15) * 72 + ks * 32 + quad * 8);
        accV[nt] = MFMA_BF16(paV[ks].hi, bv, accV[nt]);
        accV[nt] = MFMA_BF16(paV[ks].lo, bv, accV[nt]);
        bf16x8 bk = *(const bf16x8*)(sKT + (nt * 16 + l15) * 72 + ks * 32 + quad * 8);
        accK[nt] = MFMA_BF16(paK[ks].hi, bk, accK[nt]);
        accK[nt] = MFMA_BF16(paK[ks].lo, bk, accK[nt]);
      }
#pragma unroll
    for (int nt = 0; nt < 4; nt++) {
      int col = hf * 64 + nt * 16 + l15;
#pragma unroll
      for (int r = 0; r < 4; r++) {
        int row = w * 16 + quad * 4 + r;
        size_t o = ((size_t)h * 4096 + s0 + row) * 128 + col;
        vi[o] = accV[nt][r];
        kcdn[o] = f2bf(-accK[nt][r]);
      }
    }
  }
}

// ---------------------------------------------------------------------------
// phase B: sequential 64-chunk scan. grid = 32 heads x 8 col-groups (16 dv).
__global__ __launch_bounds__(256) void k_phaseB(const bf16_t* __restrict__ qb,
                                                const bf16_t* __restrict__ kbT,
                                                const float* __restrict__ g,
                                                const float* __restrict__ vi,
                                                const bf16_t* __restrict__ kcdn,
                                                bf16_t* __restrict__ vnT,
                                                bf16_t* __restrict__ outp) {
  __shared__ __align__(16) char smem[13312];
  float* sGc2 = (float*)smem;                 // [2][64] -> 512
  unsigned* sSTp = (unsigned*)(smem + 512);   // [16][132] -> ends 8960
  unsigned* sVTp = (unsigned*)(smem + 8960);  // [16][68] -> ends 13312
  const int tid = threadIdx.x, lane = tid & 63, w = tid >> 6;
  const int quad = lane >> 4, l15 = lane & 15;
  const int h = blockIdx.x >> 3, cg = blockIdx.x & 7;
  const int kh = h >> 1, col0 = cg * 16;
  const int m = w * 16 + l15;

  for (int i = tid; i < 16 * 132; i += 256) sSTp[i] = 0u;
  if (tid < 64) {
    float gv = g[(size_t)tid * 32 + h];
#pragma unroll
    for (int off = 1; off < 64; off <<= 1) {
      float t = __shfl_up(gv, off, 64);
      if (tid >= off) gv += t;
    }
    sGc2[tid] = gv;
  }
  __syncthreads();

  for (int ci = 0; ci < 64; ci++) {
    const int s0 = ci * 64;
    const float* sGc = sGc2 + (ci & 1) * 64;

    // per-chunk global fragments (state-independent; overlap with ds_reads)
    const bf16_t* kcrow = kcdn + ((size_t)h * 4096 + s0 + m) * 128;
    const bf16_t* qrow = qb + (size_t)(s0 + m) * 2048 + kh * 128;
    bf16x8 a1[4], a2[4], kT[2][2];
#pragma unroll
    for (int d = 0; d < 4; d++) {
      a1[d] = *(const bf16x8*)(kcrow + d * 32 + quad * 8);
      a2[d] = *(const bf16x8*)(qrow + d * 32 + quad * 8);
    }
#pragma unroll
    for (int mi = 0; mi < 2; mi++)
#pragma unroll
      for (int ks = 0; ks < 2; ks++)
        kT[mi][ks] = *(const bf16x8*)(kbT + ((size_t)(kh * 64 + ci) * 128 +
                                             w * 32 + mi * 16 + l15) * 64 + ks * 32 + quad * 8);
    const int colg = col0 + l15;
    size_t vbase = ((size_t)h * 4096 + s0 + w * 16 + quad * 4) * 128 + colg;
    f32x4 accV = {vi[vbase], vi[vbase + 128], vi[vbase + 256], vi[vbase + 384]};
    f32x4 accO = {0.f, 0.f, 0.f, 0.f};
#pragma unroll
    for (int d = 0; d < 4; d++) {
      unsigned u[8];
      load8u(u, sSTp + l15 * 132 + d * 32 + quad * 8);
      FragPair B = unpack8(u);
      accV = MFMA_BF16(a1[d], B.hi, accV);
      accV = MFMA_BF16(a1[d], B.lo, accV);
      accO = MFMA_BF16(a2[d], B.hi, accO);
      accO = MFMA_BF16(a2[d], B.lo, accO);
    }
    const float gl = sGc[63];
    {
      bf16_t* vout = vnT + ((size_t)(h * 64 + ci) * 128 + colg) * 64 + w * 16 + quad * 4;
      bf16_t* oout = outp + vbase;
      ushort4 vv;
      unsigned pk[4];
      unsigned short vb_[4];
#pragma unroll
      for (int r = 0; r < 4; r++) {
        float gr = sGc[w * 16 + quad * 4 + r];
        oout[(size_t)r * 128] = f2bf(accO[r] * __expf(gr));
        vb_[r] = __builtin_bit_cast(unsigned short, f2bf(accV[r]));
        pk[r] = packhl(accV[r] * __expf(gl - gr));  // fold decay into v_new
      }
      vv.x = vb_[0]; vv.y = vb_[1]; vv.z = vb_[2]; vv.w = vb_[3];
      *(ushort4*)vout = vv;
      uint4 pv; pv.x = pk[0]; pv.y = pk[1]; pv.z = pk[2]; pv.w = pk[3];
      *(uint4*)(sVTp + l15 * 68 + w * 16 + quad * 4) = pv;
    }
    __syncthreads();  // state reads done + sVTp visible

    // state = state*e^gl + kT @ (decayed v_new)
    f32x4 accD[2];
#pragma unroll
    for (int mi = 0; mi < 2; mi++) { f32x4 z = {0.f, 0.f, 0.f, 0.f}; accD[mi] = z; }
#pragma unroll
    for (int ks = 0; ks < 2; ks++) {
      unsigned u[8];
      load8u(u, sVTp + l15 * 68 + ks * 32 + quad * 8);
      FragPair Bv = unpack8(u);
#pragma unroll
      for (int mi = 0; mi < 2; mi++) {
        accD[mi] = MFMA_BF16(kT[mi][ks], Bv.hi, accD[mi]);
        accD[mi] = MFMA_BF16(kT[mi][ks], Bv.lo, accD[mi]);
      }
    }
    float egl = __expf(gl);
#pragma unroll
    for (int mi = 0; mi < 2; mi++) {
      int row0 = w * 32 + mi * 16 + quad * 4;
      unsigned* ps = sSTp + l15 * 132 + row0;
      uint4 old4 = *(uint4*)ps;
      uint4 nu;
      nu.x = packhl(upk(old4.x) * egl + accD[mi][0]);
      nu.y = packhl(upk(old4.y) * egl + accD[mi][1]);
      nu.z = packhl(upk(old4.z) * egl + accD[mi][2]);
      nu.w = packhl(upk(old4.w) * egl + accD[mi][3]);
      *(uint4*)ps = nu;
    }
    // next chunk's gcum into the other sGc buffer (race-free: other half)
    if (ci + 1 < 64 && tid < 64) {
      float gv = g[(size_t)((ci + 1) * 64 + tid) * 32 + h];
#pragma unroll
      for (int off = 1; off < 64; off <<= 1) {
        float t = __shfl_up(gv, off, 64);
        if (tid >= off) gv += t;
      }
      sGc2[((ci + 1) & 1) * 64 + tid] = gv;
    }
    __syncthreads();
  }
}

// ---------------------------------------------------------------------------
// phase C: a = tril(q@k^T * decay); out = outp + a @ v_new; gated RMSNorm -> xf bf16
__global__ __launch_bounds__(256) void k_phaseC(const bf16_t* __restrict__ qb,
                                                const bf16_t* __restrict__ kb,
                                                const float* __restrict__ g,
                                                const bf16_t* __restrict__ vnT,
                                                const bf16_t* __restrict__ outp,
                                                const bf16_t* __restrict__ zb,
                                                const float* __restrict__ nw,
                                                bf16_t* __restrict__ xf) {
  __shared__ __align__(16) char smem[17664];
  float* sGc = (float*)smem;                 // [64]
  unsigned* sAp = (unsigned*)(smem + 256);   // [64][68] hi/lo packed
  const int tid = threadIdx.x, lane = tid & 63, w = tid >> 6;
  const int quad = lane >> 4, l15 = lane & 15;
  const int h = blockIdx.x >> 6, ci = blockIdx.x & 63;
  const int kh = h >> 1, s0 = ci * 64;
  const int m = w * 16 + l15;

  if (tid < 64) {
    float gv = g[(size_t)(s0 + tid) * 32 + h];
#pragma unroll
    for (int off = 1; off < 64; off <<= 1) {
      float t = __shfl_up(gv, off, 64);
      if (tid >= off) gv += t;
    }
    sGc[tid] = gv;
  }
  __syncthreads();

  const bf16_t* qrow = qb + (size_t)s0 * 2048 + kh * 128;
  const bf16_t* krow = kb + (size_t)s0 * 2048 + kh * 128;
  bf16x8 aq[4];
#pragma unroll
  for (int ks = 0; ks < 4; ks++)
    aq[ks] = *(const bf16x8*)(qrow + (size_t)m * 2048 + ks * 32 + quad * 8);
  f32x4 accA[4];
#pragma unroll
  for (int nt = 0; nt < 4; nt++) { f32x4 z = {0.f, 0.f, 0.f, 0.f}; accA[nt] = z; }
#pragma unroll
  for (int nt = 0; nt < 4; nt++)
#pragma unroll
    for (int ks = 0; ks < 4; ks++) {
      bf16x8 bk = *(const bf16x8*)(krow + (size_t)(nt * 16 + l15) * 2048 + ks * 32 + quad * 8);
      accA[nt] = MFMA_BF16(aq[ks], bk, accA[nt]);
    }
#pragma unroll
  for (int nt = 0; nt < 4; nt++) {
    int j = nt * 16 + l15;
#pragma unroll
    for (int r = 0; r < 4; r++) {
      int i = w * 16 + quad * 4 + r;
      float a = (i >= j) ? accA[nt][r] * __expf(sGc[i] - sGc[j]) : 0.f;
      sAp[i * 68 + j] = packhl(a);
    }
  }
  __syncthreads();

  FragPair Aa[2];
#pragma unroll
  for (int ks = 0; ks < 2; ks++) {
    unsigned u[8];
    load8u(u, sAp + m * 68 + ks * 32 + quad * 8);
    Aa[ks] = unpack8(u);
  }
  f32x4 accO[8];
#pragma unroll
  for (int nt = 0; nt < 8; nt++) {
    size_t base = ((size_t)h * 4096 + s0 + w * 16 + quad * 4) * 128 + nt * 16 + l15;
    f32x4 z;
    z[0] = bf2f(outp[base]); z[1] = bf2f(outp[base + 128]);
    z[2] = bf2f(outp[base + 256]); z[3] = bf2f(outp[base + 384]);
    accO[nt] = z;
  }
#pragma unroll
  for (int nt = 0; nt < 8; nt++)
#pragma unroll
    for (int ks = 0; ks < 2; ks++) {
      bf16x8 bv = *(const bf16x8*)(vnT + ((size_t)(h * 64 + ci) * 128 + nt * 16 + l15) * 64 +
                                   ks * 32 + quad * 8);
      accO[nt] = MFMA_BF16(Aa[ks].hi, bv, accO[nt]);
      accO[nt] = MFMA_BF16(Aa[ks].lo, bv, accO[nt]);
    }

  // gated RMSNorm: xf = core*silu(z); xf *= rsqrt(mean(xf^2)+eps)*norm_w
  float xv[8][4];
  float ss[4] = {0.f, 0.f, 0.f, 0.f};
#pragma unroll
  for (int nt = 0; nt < 8; nt++) {
    int dv = nt * 16 + l15;
#pragma unroll
    for (int r = 0; r < 4; r++) {
      int s = s0 + w * 16 + quad * 4 + r;
      float z = bf2f(zb[(size_t)s * 4096 + h * 128 + dv]);
      float gate = z / (1.f + __expf(-z));
      float val = accO[nt][r] * gate;
      xv[nt][r] = val;
      ss[r] += val * val;
    }
  }
#pragma unroll
  for (int off = 1; off < 16; off <<= 1) {
#pragma unroll
    for (int r = 0; r < 4; r++) ss[r] += __shfl_xor(ss[r], off, 64);
  }
  float rs[4];
#pragma unroll
  for (int r = 0; r < 4; r++) rs[r] = rsqrtf(ss[r] * (1.f / 128.f) + 1e-6f);
#pragma unroll
  for (int nt = 0; nt < 8; nt++) {
    int dv = nt * 16 + l15;
    float nwv = nw[dv];
#pragma unroll
    for (int r = 0; r < 4; r++) {
      int s = s0 + w * 16 + quad * 4 + r;
      xf[(size_t)s * 4096 + h * 128 + dv] = f2bf(xv[nt][r] * rs[r] * nwv);
    }
  }
}

// ---------------------------------------------------------------------------
extern "C" void kernel_launch(void* const* d_in, const int* in_sizes, int n_in,
                              void* d_out, int out_size, void* d_ws, size_t ws_size,
                              hipStream_t stream) {
  const float* hs = (const float*)d_in[0];
  const float* Wqkvz = (const float*)d_in[1];
  const float* Wba = (const float*)d_in[2];
  const float* convk = (const float*)d_in[3];
  const float* A_log = (const float*)d_in[4];
  const float* dtb = (const float*)d_in[5];
  const float* nw = (const float*)d_in[6];
  const float* Wout = (const float*)d_in[7];
  float* out = (float*)d_out;
  char* ws = (char*)d_ws;

  // Arena: 252,706,816 B with static aliasing.
  const size_t NEED = 252706816u;
  if (ws_size < NEED) return;  // diagnostic: absmax==max|ref| => ws too small

  bf16_t* hsbf = (bf16_t*)(ws + 0);              // 16.78 MB [t1-t2]
  bf16_t* wqkT = (bf16_t*)(ws + 16777216);       // 50.33 MB [t1-t2]
  bf16_t* qb   = (bf16_t*)(ws + 0);              // 16.78 MB [t4-t7] (over hsbf)
  bf16_t* kb   = (bf16_t*)(ws + 16777216);       // 16.78 MB [t4-t7] (over wqkT)
  bf16_t* vb   = (bf16_t*)(ws + 33554432);       // 33.55 MB [t4-t5] (over wqkT)
  bf16_t* vnT  = (bf16_t*)(ws + 33554432);       // 33.55 MB [t6-t7] (over vb)
  bf16_t* qkvb = (bf16_t*)(ws + 67108864);       // 67.11 MB [t2-t4]
  float*  vi   = (float*)(ws + 67108864);        // 67.11 MB [t5-t6] (over qkvb)
  bf16_t* xf   = (bf16_t*)(ws + 67108864);       // 33.55 MB [t7-t9] (over vi)
  bf16_t* zb   = (bf16_t*)(ws + 134217728);      // 33.55 MB [t2-t7]
  float*  gbuf = (float*)(ws + 167772160);       // 0.52 MB
  float*  bbuf = (float*)(ws + 168296448);       // 0.52 MB
  bf16_t* kcdn = (bf16_t*)(ws + 168820736);      // 33.55 MB [t5-t6]
  bf16_t* woutT= (bf16_t*)(ws + 168820736);      // 16.78 MB [t8-t9] (over kcdn)
  bf16_t* outp = (bf16_t*)(ws + 202375168);      // 33.55 MB [t6-t7]
  bf16_t* kbT  = (bf16_t*)(ws + 235929600);      // 16.78 MB [t4.5-t6] -> ends 252,706,816

  k_cvt<<<8192, 256, 0, stream>>>(hs, hsbf, 4096 * 2048);                      // t1
  k_transpose_cvt<<<dim3(192, 32), 256, 0, stream>>>(Wqkvz, wqkT, 2048, 12288);
  k_gemm_qkvz<<<dim3(48, 16), 512, 0, stream>>>(hsbf, wqkT, qkvb, zb,          // t2
                                                4096, 12288, 2048);
  k_ba<<<128, 256, 0, stream>>>(hs, Wba, A_log, dtb, gbuf, bbuf);              // t3
  k_conv<<<dim3(32, 32), 256, 0, stream>>>(qkvb, convk, qb, kb, vb);           // t4
  k_ktrans<<<1024, 256, 0, stream>>>(kb, kbT);                                 // t4.5
  k_phaseA<<<2048, 256, 0, stream>>>(kb, vb, gbuf, bbuf, vi, kcdn);            // t5
  k_phaseB<<<256, 256, 0, stream>>>(qb, kbT, gbuf, vi, kcdn, vnT, outp);       // t6
  k_phaseC<<<2048, 256, 0, stream>>>(qb, kb, gbuf, vnT, outp, zb, nw, xf);     // t7
  k_transpose_cvt<<<dim3(32, 64), 256, 0, stream>>>(Wout, woutT, 4096, 2048);  // t8
  k_gemm<<<dim3(16, 32), 256, 0, stream>>>(xf, woutT, out, 4096, 2048, 4096);  // t9
}